// Round 1
// baseline (415.655 us; speedup 1.0000x reference)
//
#include <hip/hip_runtime.h>
#include <math.h>

// GAT 2-layer: N=50000 nodes, E=800000 edges, heads=1
// dims: 128 -> 128 (BN+ReLU) -> 112 (BN)
#define NN 50000
#define NPAD 50048               // 782 * 64, MFMA row tiles
#define NE 800000
#define SCAN_B 256
#define SCAN_NBLK ((NN + SCAN_B - 1) / SCAN_B)   // 196
#define AGG_NBLK 2048

typedef __attribute__((ext_vector_type(8))) short bf16x8;           // MFMA A/B frag
typedef __attribute__((ext_vector_type(4))) float f32x4;            // MFMA C/D frag
typedef __attribute__((ext_vector_type(8))) unsigned short u16x8;   // 16B gather

__device__ __forceinline__ unsigned short f2bf(float x) {
    unsigned u = __float_as_uint(x);
    u += 0x7fffu + ((u >> 16) & 1);              // round-to-nearest-even
    return (unsigned short)(u >> 16);
}
__device__ __forceinline__ float bf2f(unsigned short h) {
    return __uint_as_float(((unsigned)h) << 16);
}

// nontemporal 8B record helpers (keep xs gather set resident in L2)
__device__ __forceinline__ uint2 ldnt_u2(const uint2* p) {
    unsigned long long v = __builtin_nontemporal_load(
        reinterpret_cast<const unsigned long long*>(p));
    uint2 r; r.x = (unsigned)v; r.y = (unsigned)(v >> 32); return r;
}
__device__ __forceinline__ void stnt_u2(uint2* p, uint2 v) {
    unsigned long long u = ((unsigned long long)v.y << 32) | (unsigned long long)v.x;
    __builtin_nontemporal_store(u, reinterpret_cast<unsigned long long*>(p));
}

// ---------------- init: deg/stats zero + ve fold + W split-transpose ----------------
// ve[0..7] = We0 @ a_edge0 ; ve[8..15] = We1 @ a_edge1   (heads=1 folding)
__global__ void k_init_cvt(int* __restrict__ deg, float* __restrict__ stats,
                           const float* __restrict__ We0, const float* __restrict__ ae0,
                           const float* __restrict__ We1, const float* __restrict__ ae1,
                           float* __restrict__ ve,
                           const float* __restrict__ W0, const float* __restrict__ W1,
                           unsigned short* __restrict__ Wth0, unsigned short* __restrict__ Wtl0,
                           unsigned short* __restrict__ Wth1, unsigned short* __restrict__ Wtl1)
{
    int idx = blockIdx.x * 256 + threadIdx.x;
    if (idx < NN) deg[idx] = 0;
    if (idx < 512) stats[idx] = 0.f;
    if (idx < 128 * 128) {
        int k = idx / 128, c = idx % 128;
        float v = W0[idx];
        unsigned short hi = f2bf(v);
        Wth0[c * 128 + k] = hi;
        Wtl0[c * 128 + k] = f2bf(v - bf2f(hi));
    } else if (idx < 128 * 128 + 128 * 112) {
        int i2 = idx - 128 * 128;
        int k = i2 / 112, c = i2 % 112;
        float v = W1[i2];
        unsigned short hi = f2bf(v);
        Wth1[c * 128 + k] = hi;
        Wtl1[c * 128 + k] = f2bf(v - bf2f(hi));
    }
    if (blockIdx.x == gridDim.x - 1) {
        int j = threadIdx.x;
        if (j < 8) {
            float s = 0.f;
            for (int c = 0; c < 128; ++c) s += We0[j * 128 + c] * ae0[c];
            ve[j] = s;
        } else if (j < 16) {
            int jj = j - 8;
            float s = 0.f;
            for (int c = 0; c < 112; ++c) s += We1[jj * 112 + c] * ae1[c];
            ve[8 + jj] = s;
        }
    }
}

// ---------------- CSR build ----------------
__global__ void k_deg(const int* __restrict__ dst, int* __restrict__ deg, int E_)
{
    int e = blockIdx.x * blockDim.x + threadIdx.x;
    if (e < E_) atomicAdd(&deg[dst[e]], 1);
}

__global__ void k_scan1(const int* __restrict__ deg, int* __restrict__ partial)
{
    __shared__ int sm[SCAN_B];
    int t = threadIdx.x;
    int idx = blockIdx.x * SCAN_B + t;
    sm[t] = (idx < NN) ? deg[idx] : 0;
    __syncthreads();
    #pragma unroll
    for (int off = SCAN_B / 2; off > 0; off >>= 1) {
        if (t < off) sm[t] += sm[t + off];
        __syncthreads();
    }
    if (t == 0) partial[blockIdx.x] = sm[0];
}

// fused stage 2+3: each block computes its own prefix over partials, then local scan
__global__ void k_scan3(const int* __restrict__ deg, const int* __restrict__ partial,
                        int* __restrict__ rp, int* __restrict__ cur)
{
    __shared__ int sm[SCAN_B];
    __shared__ int pbase;
    int t = threadIdx.x;
    int pv = (t < SCAN_NBLK && t < blockIdx.x) ? partial[t] : 0;
    sm[t] = pv;
    __syncthreads();
    #pragma unroll
    for (int off = SCAN_B / 2; off > 0; off >>= 1) {
        if (t < off) sm[t] += sm[t + off];
        __syncthreads();
    }
    if (t == 0) pbase = sm[0];
    __syncthreads();
    int idx = blockIdx.x * SCAN_B + t;
    int v = (idx < NN) ? deg[idx] : 0;
    sm[t] = v;
    __syncthreads();
    #pragma unroll
    for (int off = 1; off < SCAN_B; off <<= 1) {
        int u = (t >= off) ? sm[t - off] : 0;
        __syncthreads();
        sm[t] += u;
        __syncthreads();
    }
    int excl = pbase + ((t == 0) ? 0 : sm[t - 1]);
    if (idx < NN) { rp[idx] = excl; cur[idx] = excl; }
    if (idx == NN - 1) rp[NN] = excl + v;
}

// ---------------- edge pack: 8B records {src, bf16 a0 | bf16 a1<<16}, CSR order ----------------
__global__ void k_csr_fill(const int* __restrict__ src, const int* __restrict__ dst,
                           const float* __restrict__ eatt, const float* __restrict__ ve,
                           int* __restrict__ cur, uint2* __restrict__ pack, int E_)
{
    int e = blockIdx.x * blockDim.x + threadIdx.x;
    if (e >= E_) return;
    const float4* ea = reinterpret_cast<const float4*>(eatt + (size_t)e * 8);
    float4 e0 = ea[0], e1 = ea[1];
    float a0 = e0.x * ve[0] + e0.y * ve[1] + e0.z * ve[2] + e0.w * ve[3]
             + e1.x * ve[4] + e1.y * ve[5] + e1.z * ve[6] + e1.w * ve[7];
    float a1 = e0.x * ve[8] + e0.y * ve[9] + e0.z * ve[10] + e0.w * ve[11]
             + e1.x * ve[12] + e1.y * ve[13] + e1.z * ve[14] + e1.w * ve[15];
    int d = dst[e];
    int pos = atomicAdd(&cur[d], 1);
    uint2 rec;
    rec.x = (unsigned)src[e];
    rec.y = (unsigned)f2bf(a0) | ((unsigned)f2bf(a1) << 16);
    pack[pos] = rec;
}

// ---------------- MFMA GEMM: one wave = 16 rows x COLS, bf16x3 split precision ----------------
template<int COLS, bool BN_IN>
__global__ void k_gemm_mfma(const float* __restrict__ A,
                            const unsigned short* __restrict__ Wth,
                            const unsigned short* __restrict__ Wtl,
                            unsigned short* __restrict__ out,
                            const float* __restrict__ a_src, const float* __restrict__ a_dst,
                            float* __restrict__ als, float* __restrict__ ald,
                            const float* __restrict__ bsum, const float* __restrict__ bsq,
                            const float* __restrict__ gamma, const float* __restrict__ beta)
{
    constexpr int NT = COLS / 16;
    __shared__ float scN[128], shN[128];
    if (BN_IN) {
        if (threadIdx.x < 128) {
            int k = threadIdx.x;
            float invn = 1.0f / (float)NN;
            float mean = bsum[k] * invn;
            float var  = bsq[k] * invn - mean * mean;
            float sc = gamma[k] * rsqrtf(var + 1e-5f);
            scN[k] = sc;
            shN[k] = beta[k] - mean * sc;
        }
        __syncthreads();
    }
    int wv = threadIdx.x >> 6;
    int lane = threadIdx.x & 63;
    int r0 = blockIdx.x * 64 + wv * 16;
    int m = lane & 15;
    int quad = lane >> 4;
    int arow = r0 + m;
    int rc = (arow < NN) ? arow : NN - 1;    // clamp: pad rows computed but never stored
    const float* pa = A + (size_t)rc * 128 + quad * 8;

    f32x4 acc[NT];
    #pragma unroll
    for (int t = 0; t < NT; ++t) acc[t] = f32x4{0.f, 0.f, 0.f, 0.f};

    #pragma unroll
    for (int ks = 0; ks < 4; ++ks) {
        float4 v0 = *reinterpret_cast<const float4*>(pa + ks * 32);
        float4 v1 = *reinterpret_cast<const float4*>(pa + ks * 32 + 4);
        float vv[8] = {v0.x, v0.y, v0.z, v0.w, v1.x, v1.y, v1.z, v1.w};
        int kb = ks * 32 + quad * 8;
        bf16x8 ah, al;
        #pragma unroll
        for (int jj = 0; jj < 8; ++jj) {
            float f = vv[jj];
            if (BN_IN) f = fmaxf(f * scN[kb + jj] + shN[kb + jj], 0.f);
            unsigned short hi = f2bf(f);
            ah[jj] = (short)hi;
            al[jj] = (short)f2bf(f - bf2f(hi));
        }
        #pragma unroll
        for (int t = 0; t < NT; ++t) {
            size_t boff = (size_t)(t * 16 + m) * 128 + ks * 32 + quad * 8;
            bf16x8 bh = *reinterpret_cast<const bf16x8*>(Wth + boff);
            bf16x8 bl = *reinterpret_cast<const bf16x8*>(Wtl + boff);
            acc[t] = __builtin_amdgcn_mfma_f32_16x16x32_bf16(ah, bh, acc[t], 0, 0, 0);
            acc[t] = __builtin_amdgcn_mfma_f32_16x16x32_bf16(al, bh, acc[t], 0, 0, 0);
            acc[t] = __builtin_amdgcn_mfma_f32_16x16x32_bf16(ah, bl, acc[t], 0, 0, 0);
        }
    }

    // epilogue: bf16 store + fused attention dots (C/D: col=lane&15, row=quad*4+reg)
    float p[4] = {0.f, 0.f, 0.f, 0.f}, q[4] = {0.f, 0.f, 0.f, 0.f};
    #pragma unroll
    for (int t = 0; t < NT; ++t) {
        int c = t * 16 + m;
        float asv = a_src[c], adv = a_dst[c];
        #pragma unroll
        for (int rI = 0; rI < 4; ++rI) {
            float v = acc[t][rI];
            int row = r0 + quad * 4 + rI;
            if (row < NN) out[(size_t)row * COLS + c] = f2bf(v);
            p[rI] += v * asv;
            q[rI] += v * adv;
        }
    }
    #pragma unroll
    for (int rI = 0; rI < 4; ++rI) {
        #pragma unroll
        for (int off = 1; off <= 8; off <<= 1) {
            p[rI] += __shfl_xor(p[rI], off);
            q[rI] += __shfl_xor(q[rI], off);
        }
    }
    if (m == 0) {
        #pragma unroll
        for (int rI = 0; rI < 4; ++rI) {
            int row = r0 + quad * 4 + rI;
            if (row < NN) { als[row] = p[rI]; ald[row] = q[rI]; }
        }
    }
}

// ---------------- per-edge logit+exp precompute (hoisted off the aggregate chain) -------
// quarter-wave (16 lanes) per dst node; coalesced pack reads; writes {src, exp(alpha)} f32.
// Edge-parallel and massively launched -> gather latency fully hidden by TLP.
template<int LAYER>
__global__ void k_logit(const int* __restrict__ rp, const uint2* __restrict__ pack,
                        const float* __restrict__ als, const float* __restrict__ ald,
                        uint2* __restrict__ pe)
{
    int wv = threadIdx.x >> 6;
    int lane = threadIdx.x & 63;
    int q = lane >> 4;
    int ql = lane & 15;
    int w = blockIdx.x * 16 + wv * 4 + q;
    if (w >= NN) return;
    int beg = rp[w], end = rp[w + 1];
    float aldv = ald[w];
    for (int p = beg + ql; p < end; p += 16) {
        uint2 r = pack[p];
        float a = als[r.x] + aldv
                + bf2f((unsigned short)(LAYER ? (r.y >> 16) : (r.y & 0xffffu)));
        a = a > 0.f ? a : 0.2f * a;
        uint2 o;
        o.x = r.x;
        o.y = __float_as_uint(__expf(a));
        stnt_u2(pe + p, o);
    }
}

// ---------------- per-dst aggregate: grid-stride, quarter-wave edge split, fused BN partials --
// Dependent chain is now a single hop: pe record (coalesced, L2) -> xs gather -> FMA.
// 16 lanes per edge, u16x8 (16B) per lane; 4 edges/quarter in flight (16 edges/pass).
template<int COLS>
__global__ void k_aggregate(const int* __restrict__ rp, const uint2* __restrict__ pe,
                            const unsigned short* __restrict__ xs, float* __restrict__ out,
                            float* __restrict__ psum, float* __restrict__ psq)
{
    __shared__ float sS[4 * 128], sQ[4 * 128];
    int wv = threadIdx.x >> 6;
    int lane = threadIdx.x & 63;
    int q = lane >> 4;               // quarter 0..3 -> edge slot
    int ql = lane & 15;
    int col = ql * 8;
    bool act = (col < COLS);
    float bs[8] = {0.f,0.f,0.f,0.f,0.f,0.f,0.f,0.f};
    float bq[8] = {0.f,0.f,0.f,0.f,0.f,0.f,0.f,0.f};

    for (int w = blockIdx.x * 4 + wv; w < NN; w += AGG_NBLK * 4) {
        int beg = rp[w], end = rp[w + 1];
        float acc[8] = {0.f,0.f,0.f,0.f,0.f,0.f,0.f,0.f};
        float den = 0.f;
        int j = beg;
        // 16 edges/pass: 4 independent gathers in flight per lane
        for (; j + 16 <= end; j += 16) {
            uint2 r0 = ldnt_u2(pe + j + q);
            uint2 r1 = ldnt_u2(pe + j + 4 + q);
            uint2 r2 = ldnt_u2(pe + j + 8 + q);
            uint2 r3 = ldnt_u2(pe + j + 12 + q);
            float e0 = __uint_as_float(r0.y);
            float e1 = __uint_as_float(r1.y);
            float e2 = __uint_as_float(r2.y);
            float e3 = __uint_as_float(r3.y);
            den += (e0 + e1) + (e2 + e3);
            if (act) {
                u16x8 u0 = *reinterpret_cast<const u16x8*>(xs + (size_t)r0.x * COLS + col);
                u16x8 u1 = *reinterpret_cast<const u16x8*>(xs + (size_t)r1.x * COLS + col);
                u16x8 u2 = *reinterpret_cast<const u16x8*>(xs + (size_t)r2.x * COLS + col);
                u16x8 u3 = *reinterpret_cast<const u16x8*>(xs + (size_t)r3.x * COLS + col);
                #pragma unroll
                for (int k = 0; k < 8; ++k)
                    acc[k] += (e0 * bf2f(u0[k]) + e1 * bf2f(u1[k]))
                            + (e2 * bf2f(u2[k]) + e3 * bf2f(u3[k]));
            }
        }
        // 8 edges/pass
        for (; j + 8 <= end; j += 8) {
            uint2 r0 = ldnt_u2(pe + j + q);
            uint2 r1 = ldnt_u2(pe + j + 4 + q);
            float e0 = __uint_as_float(r0.y);
            float e1 = __uint_as_float(r1.y);
            den += e0 + e1;
            if (act) {
                u16x8 u0 = *reinterpret_cast<const u16x8*>(xs + (size_t)r0.x * COLS + col);
                u16x8 u1 = *reinterpret_cast<const u16x8*>(xs + (size_t)r1.x * COLS + col);
                #pragma unroll
                for (int k = 0; k < 8; ++k)
                    acc[k] += e0 * bf2f(u0[k]) + e1 * bf2f(u1[k]);
            }
        }
        // remainder, 4 edges/pass with per-quarter guard
        for (; j < end; j += 4) {
            int jj = j + q;
            if (jj < end) {
                uint2 r = ldnt_u2(pe + jj);
                float ex = __uint_as_float(r.y);
                den += ex;
                if (act) {
                    u16x8 u = *reinterpret_cast<const u16x8*>(xs + (size_t)r.x * COLS + col);
                    #pragma unroll
                    for (int k = 0; k < 8; ++k)
                        acc[k] += ex * bf2f(u[k]);
                }
            }
        }
        #pragma unroll
        for (int k = 0; k < 8; ++k) {
            acc[k] += __shfl_xor(acc[k], 16);
            acc[k] += __shfl_xor(acc[k], 32);
        }
        den += __shfl_xor(den, 16);
        den += __shfl_xor(den, 32);
        float inv = (end > beg) ? 1.f / den : 0.f;
        if (q == 0 && act) {
            float o[8];
            #pragma unroll
            for (int k = 0; k < 8; ++k) {
                o[k] = acc[k] * inv;
                bs[k] += o[k];
                bq[k] += o[k] * o[k];
            }
            f32x4 o0 = {o[0], o[1], o[2], o[3]};
            f32x4 o1 = {o[4], o[5], o[6], o[7]};
            __builtin_nontemporal_store(o0, reinterpret_cast<f32x4*>(out + (size_t)w * COLS + col));
            __builtin_nontemporal_store(o1, reinterpret_cast<f32x4*>(out + (size_t)w * COLS + col + 4));
        }
    }
    // fold BN partials across the block's 4 waves
    if (q == 0) {
        #pragma unroll
        for (int k = 0; k < 8; ++k) {
            sS[wv * 128 + col + k] = bs[k];
            sQ[wv * 128 + col + k] = bq[k];
        }
    }
    __syncthreads();
    int t = threadIdx.x;
    if (t < 128) {
        psum[(size_t)blockIdx.x * 128 + t] = sS[t] + sS[128 + t] + sS[256 + t] + sS[384 + t];
        psq [(size_t)blockIdx.x * 128 + t] = sQ[t] + sQ[128 + t] + sQ[256 + t] + sQ[384 + t];
    }
}

// ---------------- BN stats stage 2: reduce AGG_NBLK partials (lightly-contended atomics) ----
__global__ void k_bn_stats2(const float* __restrict__ psum, const float* __restrict__ psq,
                            float* __restrict__ sums, float* __restrict__ sqs)
{
    int t = threadIdx.x;
    int c = t & 127;
    constexpr int ROWS = AGG_NBLK / 128;    // 16
    const float* sp = (t < 128) ? psum : psq;
    float s = 0.f;
    #pragma unroll 4
    for (int i = 0; i < ROWS; ++i)
        s += sp[(size_t)(blockIdx.x * ROWS + i) * 128 + c];
    unsafeAtomicAdd(((t < 128) ? sums : sqs) + c, s);
}

// ---------------- batchnorm apply (final layer -> d_out) ----------------
template<int COLS>
__global__ void k_bn_apply(const float* __restrict__ in, float* __restrict__ out,
                           const float* __restrict__ sums, const float* __restrict__ sqs,
                           const float* __restrict__ gamma, const float* __restrict__ beta,
                           int n)
{
    int idx = blockIdx.x * blockDim.x + threadIdx.x;
    if (idx >= n * COLS) return;
    int c = idx % COLS;
    float invn = 1.0f / (float)n;
    float mean = sums[c] * invn;
    float var  = sqs[c] * invn - mean * mean;     // biased, matches jnp var
    float sc = gamma[c] * rsqrtf(var + 1e-5f);
    float sh = beta[c] - mean * sc;
    out[idx] = in[idx] * sc + sh;
}

extern "C" void kernel_launch(void* const* d_in, const int* in_sizes, int n_in,
                              void* d_out, int out_size, void* d_ws, size_t ws_size,
                              hipStream_t stream)
{
    const float* x    = (const float*)d_in[0];
    const int*   eidx = (const int*)d_in[1];
    const float* eatt = (const float*)d_in[2];
    const float* W0   = (const float*)d_in[3];
    const float* as0  = (const float*)d_in[4];
    const float* ad0  = (const float*)d_in[5];
    const float* We0  = (const float*)d_in[6];
    const float* ae0  = (const float*)d_in[7];
    // d_in[8] = b0 : cancels through BN
    const float* W1   = (const float*)d_in[9];
    const float* as1  = (const float*)d_in[10];
    const float* ad1  = (const float*)d_in[11];
    const float* We1  = (const float*)d_in[12];
    const float* ae1  = (const float*)d_in[13];
    // d_in[14] = b1 : cancels through BN
    const float* bng  = (const float*)d_in[15];
    const float* bnb  = (const float*)d_in[16];
    const float* bnfg = (const float*)d_in[17];
    const float* bnfb = (const float*)d_in[18];

    const int N = NN, E = NE;
    const int* src = eidx;
    const int* dst = eidx + E;

    float* ws = (float*)d_ws;
    size_t off = 0;
    unsigned short* xs0b = (unsigned short*)(ws + off); off += (size_t)N * 64;   // N*128 bf16
    float* h   = ws + off;      off += (size_t)N * 128;                          // fp32 25.6MB
    unsigned short* xs1b = (unsigned short*)(ws + off); off += (size_t)N * 56;   // N*112 bf16
    uint2* pack = (uint2*)(ws + off);   off += (size_t)E * 2;                    // 8B/edge
    int*   rp   = (int*)(ws + off);     off += N + 2;
    int*   cur  = (int*)(ws + off);     off += N;
    int*   deg  = (int*)(ws + off);     off += N;
    float* als0 = ws + off;     off += N;
    float* ald0 = ws + off;     off += N;
    float* als1 = ws + off;     off += N;
    float* ald1 = ws + off;     off += N;
    float* stats = ws + off;    off += 512;
    float* ve = ws + off;       off += 16;
    int*   partial = (int*)(ws + off);  off += SCAN_NBLK;
    float* psum = ws + off;     off += (size_t)AGG_NBLK * 128;
    float* psq  = ws + off;     off += (size_t)AGG_NBLK * 128;
    unsigned short* Wth0 = (unsigned short*)(ws + off); off += 128 * 64;         // 128x128 bf16
    unsigned short* Wtl0 = (unsigned short*)(ws + off); off += 128 * 64;
    unsigned short* Wth1 = (unsigned short*)(ws + off); off += 112 * 64;         // 112x128 bf16
    unsigned short* Wtl1 = (unsigned short*)(ws + off); off += 112 * 64;
    float* out1 = h;            // alias: h (fp32) dead after layer-1 gemm consumes it

    // pe: per-edge {src, exp(alpha)} records, 6.4MB. Carved out of d_out (22.4MB),
    // which is dead until k_bn_apply fully overwrites it at the end.
    uint2* pe = (uint2*)d_out;

    float* sum0 = stats;
    float* sq0  = stats + 128;
    float* sum1 = stats + 256;
    float* sq1  = stats + 384;

    // ---- init (ws poisoned 0xAA before every call) ----
    k_init_cvt<<<(N + 255) / 256, 256, 0, stream>>>(deg, stats, We0, ae0, We1, ae1, ve,
                                                    W0, W1, Wth0, Wtl0, Wth1, Wtl1);

    // ---- CSR build: deg -> scan -> direct fill (50K cursors: no hot-counter chains) ----
    k_deg<<<(E + 255) / 256, 256, 0, stream>>>(dst, deg, E);
    k_scan1<<<SCAN_NBLK, SCAN_B, 0, stream>>>(deg, partial);
    k_scan3<<<SCAN_NBLK, SCAN_B, 0, stream>>>(deg, partial, rp, cur);
    k_csr_fill<<<(E + 255) / 256, 256, 0, stream>>>(src, dst, eatt, ve, cur, pack, E);

    // ---- layer 0: 128 -> 128 ----
    k_gemm_mfma<128, false><<<NPAD / 64, 256, 0, stream>>>(x, Wth0, Wtl0, xs0b,
                                                           as0, ad0, als0, ald0,
                                                           nullptr, nullptr, nullptr, nullptr);
    k_logit<0><<<(N + 15) / 16, 256, 0, stream>>>(rp, pack, als0, ald0, pe);
    k_aggregate<128><<<AGG_NBLK, 256, 0, stream>>>(rp, pe, xs0b, h, psum, psq);
    k_bn_stats2<<<128, 256, 0, stream>>>(psum, psq, sum0, sq0);

    // ---- layer 1: 128 -> 112 (BN0+ReLU fused into GEMM A-load) ----
    k_gemm_mfma<112, true><<<NPAD / 64, 256, 0, stream>>>(h, Wth1, Wtl1, xs1b,
                                                          as1, ad1, als1, ald1,
                                                          sum0, sq0, bng, bnb);
    k_logit<1><<<(N + 15) / 16, 256, 0, stream>>>(rp, pack, als1, ald1, pe);
    k_aggregate<112><<<AGG_NBLK, 256, 0, stream>>>(rp, pe, xs1b, out1, psum, psq);
    k_bn_stats2<<<128, 256, 0, stream>>>(psum, psq, sum1, sq1);
    k_bn_apply<112><<<(N * 112 + 255) / 256, 256, 0, stream>>>(out1, (float*)d_out, sum1, sq1, bnfg, bnfb, N);
}

// Round 2
// 386.438 us; speedup vs baseline: 1.0756x; 1.0756x over previous
//
#include <hip/hip_runtime.h>
#include <math.h>

// GAT 2-layer: N=50000 nodes, E=800000 edges, heads=1
// dims: 128 -> 128 (BN+ReLU) -> 112 (BN)
#define NN 50000
#define NPAD 50048               // 782 * 64, MFMA row tiles
#define NE 800000
#define SCAN_B 256
#define SCAN_NBLK ((NN + SCAN_B - 1) / SCAN_B)   // 196
#define AGG_NBLK 4096

typedef __attribute__((ext_vector_type(8))) short bf16x8;           // MFMA A/B frag
typedef __attribute__((ext_vector_type(4))) float f32x4;            // MFMA C/D frag
typedef __attribute__((ext_vector_type(8))) unsigned short u16x8;   // 16B gather

__device__ __forceinline__ unsigned short f2bf(float x) {
    unsigned u = __float_as_uint(x);
    u += 0x7fffu + ((u >> 16) & 1);              // round-to-nearest-even
    return (unsigned short)(u >> 16);
}
__device__ __forceinline__ float bf2f(unsigned short h) {
    return __uint_as_float(((unsigned)h) << 16);
}

// ---------------- init: deg/stats zero + ve fold + W split-transpose ----------------
// ve[0..7] = We0 @ a_edge0 ; ve[8..15] = We1 @ a_edge1   (heads=1 folding)
__global__ void k_init_cvt(int* __restrict__ deg, float* __restrict__ stats,
                           const float* __restrict__ We0, const float* __restrict__ ae0,
                           const float* __restrict__ We1, const float* __restrict__ ae1,
                           float* __restrict__ ve,
                           const float* __restrict__ W0, const float* __restrict__ W1,
                           unsigned short* __restrict__ Wth0, unsigned short* __restrict__ Wtl0,
                           unsigned short* __restrict__ Wth1, unsigned short* __restrict__ Wtl1)
{
    int idx = blockIdx.x * 256 + threadIdx.x;
    if (idx < NN) deg[idx] = 0;
    if (idx < 512) stats[idx] = 0.f;
    if (idx < 128 * 128) {
        int k = idx / 128, c = idx % 128;
        float v = W0[idx];
        unsigned short hi = f2bf(v);
        Wth0[c * 128 + k] = hi;
        Wtl0[c * 128 + k] = f2bf(v - bf2f(hi));
    } else if (idx < 128 * 128 + 128 * 112) {
        int i2 = idx - 128 * 128;
        int k = i2 / 112, c = i2 % 112;
        float v = W1[i2];
        unsigned short hi = f2bf(v);
        Wth1[c * 128 + k] = hi;
        Wtl1[c * 128 + k] = f2bf(v - bf2f(hi));
    }
    if (blockIdx.x == gridDim.x - 1) {
        int j = threadIdx.x;
        if (j < 8) {
            float s = 0.f;
            for (int c = 0; c < 128; ++c) s += We0[j * 128 + c] * ae0[c];
            ve[j] = s;
        } else if (j < 16) {
            int jj = j - 8;
            float s = 0.f;
            for (int c = 0; c < 112; ++c) s += We1[jj * 112 + c] * ae1[c];
            ve[8 + jj] = s;
        }
    }
}

// ---------------- CSR build ----------------
// rank[e] = old count of dst -> position of e within its segment. Free by-product
// of the degree count; removes the atomic round-trip from the fill kernel.
__global__ void k_deg(const int* __restrict__ dst, int* __restrict__ deg,
                      int* __restrict__ rank, int E_)
{
    int e = blockIdx.x * blockDim.x + threadIdx.x;
    if (e < E_) rank[e] = atomicAdd(&deg[dst[e]], 1);
}

__global__ void k_scan1(const int* __restrict__ deg, int* __restrict__ partial)
{
    __shared__ int sm[SCAN_B];
    int t = threadIdx.x;
    int idx = blockIdx.x * SCAN_B + t;
    sm[t] = (idx < NN) ? deg[idx] : 0;
    __syncthreads();
    #pragma unroll
    for (int off = SCAN_B / 2; off > 0; off >>= 1) {
        if (t < off) sm[t] += sm[t + off];
        __syncthreads();
    }
    if (t == 0) partial[blockIdx.x] = sm[0];
}

// fused stage 2+3: each block computes its own prefix over partials, then local scan
__global__ void k_scan3(const int* __restrict__ deg, const int* __restrict__ partial,
                        int* __restrict__ rp)
{
    __shared__ int sm[SCAN_B];
    __shared__ int pbase;
    int t = threadIdx.x;
    int pv = (t < SCAN_NBLK && t < blockIdx.x) ? partial[t] : 0;
    sm[t] = pv;
    __syncthreads();
    #pragma unroll
    for (int off = SCAN_B / 2; off > 0; off >>= 1) {
        if (t < off) sm[t] += sm[t + off];
        __syncthreads();
    }
    if (t == 0) pbase = sm[0];
    __syncthreads();
    int idx = blockIdx.x * SCAN_B + t;
    int v = (idx < NN) ? deg[idx] : 0;
    sm[t] = v;
    __syncthreads();
    #pragma unroll
    for (int off = 1; off < SCAN_B; off <<= 1) {
        int u = (t >= off) ? sm[t - off] : 0;
        __syncthreads();
        sm[t] += u;
        __syncthreads();
    }
    int excl = pbase + ((t == 0) ? 0 : sm[t - 1]);
    if (idx < NN) rp[idx] = excl;
    if (idx == NN - 1) rp[NN] = excl + v;
}

// ---------------- edge pack: 8B records {src, bf16 a0 | bf16 a1<<16}, CSR order ----------------
// pos = rp[dst] + rank  (precomputed) -> scatter store is fire-and-forget, no atomic.
__global__ void k_csr_fill(const int* __restrict__ src, const int* __restrict__ dst,
                           const float* __restrict__ eatt, const float* __restrict__ ve,
                           const int* __restrict__ rp, const int* __restrict__ rank,
                           uint2* __restrict__ pack, int E_)
{
    int e = blockIdx.x * blockDim.x + threadIdx.x;
    if (e >= E_) return;
    const float4* ea = reinterpret_cast<const float4*>(eatt + (size_t)e * 8);
    float4 e0 = ea[0], e1 = ea[1];
    float a0 = e0.x * ve[0] + e0.y * ve[1] + e0.z * ve[2] + e0.w * ve[3]
             + e1.x * ve[4] + e1.y * ve[5] + e1.z * ve[6] + e1.w * ve[7];
    float a1 = e0.x * ve[8] + e0.y * ve[9] + e0.z * ve[10] + e0.w * ve[11]
             + e1.x * ve[12] + e1.y * ve[13] + e1.z * ve[14] + e1.w * ve[15];
    int pos = rp[dst[e]] + rank[e];
    uint2 rec;
    rec.x = (unsigned)src[e];
    rec.y = (unsigned)f2bf(a0) | ((unsigned)f2bf(a1) << 16);
    pack[pos] = rec;
}

// ---------------- MFMA GEMM: one wave = 16 rows x COLS, bf16x3 split precision ----------------
template<int COLS, bool BN_IN>
__global__ void k_gemm_mfma(const float* __restrict__ A,
                            const unsigned short* __restrict__ Wth,
                            const unsigned short* __restrict__ Wtl,
                            unsigned short* __restrict__ out,
                            const float* __restrict__ a_src, const float* __restrict__ a_dst,
                            float* __restrict__ als, float* __restrict__ ald,
                            const float* __restrict__ bsum, const float* __restrict__ bsq,
                            const float* __restrict__ gamma, const float* __restrict__ beta)
{
    constexpr int NT = COLS / 16;
    __shared__ float scN[128], shN[128];
    if (BN_IN) {
        if (threadIdx.x < 128) {
            int k = threadIdx.x;
            float invn = 1.0f / (float)NN;
            float mean = bsum[k] * invn;
            float var  = bsq[k] * invn - mean * mean;
            float sc = gamma[k] * rsqrtf(var + 1e-5f);
            scN[k] = sc;
            shN[k] = beta[k] - mean * sc;
        }
        __syncthreads();
    }
    int wv = threadIdx.x >> 6;
    int lane = threadIdx.x & 63;
    int r0 = blockIdx.x * 64 + wv * 16;
    int m = lane & 15;
    int quad = lane >> 4;
    int arow = r0 + m;
    int rc = (arow < NN) ? arow : NN - 1;    // clamp: pad rows computed but never stored
    const float* pa = A + (size_t)rc * 128 + quad * 8;

    f32x4 acc[NT];
    #pragma unroll
    for (int t = 0; t < NT; ++t) acc[t] = f32x4{0.f, 0.f, 0.f, 0.f};

    #pragma unroll
    for (int ks = 0; ks < 4; ++ks) {
        float4 v0 = *reinterpret_cast<const float4*>(pa + ks * 32);
        float4 v1 = *reinterpret_cast<const float4*>(pa + ks * 32 + 4);
        float vv[8] = {v0.x, v0.y, v0.z, v0.w, v1.x, v1.y, v1.z, v1.w};
        int kb = ks * 32 + quad * 8;
        bf16x8 ah, al;
        #pragma unroll
        for (int jj = 0; jj < 8; ++jj) {
            float f = vv[jj];
            if (BN_IN) f = fmaxf(f * scN[kb + jj] + shN[kb + jj], 0.f);
            unsigned short hi = f2bf(f);
            ah[jj] = (short)hi;
            al[jj] = (short)f2bf(f - bf2f(hi));
        }
        #pragma unroll
        for (int t = 0; t < NT; ++t) {
            size_t boff = (size_t)(t * 16 + m) * 128 + ks * 32 + quad * 8;
            bf16x8 bh = *reinterpret_cast<const bf16x8*>(Wth + boff);
            bf16x8 bl = *reinterpret_cast<const bf16x8*>(Wtl + boff);
            acc[t] = __builtin_amdgcn_mfma_f32_16x16x32_bf16(ah, bh, acc[t], 0, 0, 0);
            acc[t] = __builtin_amdgcn_mfma_f32_16x16x32_bf16(al, bh, acc[t], 0, 0, 0);
            acc[t] = __builtin_amdgcn_mfma_f32_16x16x32_bf16(ah, bl, acc[t], 0, 0, 0);
        }
    }

    // epilogue: bf16 store + fused attention dots (C/D: col=lane&15, row=quad*4+reg)
    float p[4] = {0.f, 0.f, 0.f, 0.f}, q[4] = {0.f, 0.f, 0.f, 0.f};
    #pragma unroll
    for (int t = 0; t < NT; ++t) {
        int c = t * 16 + m;
        float asv = a_src[c], adv = a_dst[c];
        #pragma unroll
        for (int rI = 0; rI < 4; ++rI) {
            float v = acc[t][rI];
            int row = r0 + quad * 4 + rI;
            if (row < NN) out[(size_t)row * COLS + c] = f2bf(v);
            p[rI] += v * asv;
            q[rI] += v * adv;
        }
    }
    #pragma unroll
    for (int rI = 0; rI < 4; ++rI) {
        #pragma unroll
        for (int off = 1; off <= 8; off <<= 1) {
            p[rI] += __shfl_xor(p[rI], off);
            q[rI] += __shfl_xor(q[rI], off);
        }
    }
    if (m == 0) {
        #pragma unroll
        for (int rI = 0; rI < 4; ++rI) {
            int row = r0 + quad * 4 + rI;
            if (row < NN) { als[row] = p[rI]; ald[row] = q[rI]; }
        }
    }
}

// ---------------- per-edge logit+exp precompute (hoisted off the aggregate chain) -------
// quarter-wave (16 lanes) per dst node; coalesced pack reads; writes {src, exp(alpha)} f32.
// Plain stores: pe is re-read almost immediately by k_aggregate -> keep it cache-warm.
template<int LAYER>
__global__ void k_logit(const int* __restrict__ rp, const uint2* __restrict__ pack,
                        const float* __restrict__ als, const float* __restrict__ ald,
                        uint2* __restrict__ pe)
{
    int wv = threadIdx.x >> 6;
    int lane = threadIdx.x & 63;
    int q = lane >> 4;
    int ql = lane & 15;
    int w = blockIdx.x * 16 + wv * 4 + q;
    if (w >= NN) return;
    int beg = rp[w], end = rp[w + 1];
    float aldv = ald[w];
    for (int p = beg + ql; p < end; p += 16) {
        uint2 r = pack[p];
        float a = als[r.x] + aldv
                + bf2f((unsigned short)(LAYER ? (r.y >> 16) : (r.y & 0xffffu)));
        a = a > 0.f ? a : 0.2f * a;
        uint2 o;
        o.x = r.x;
        o.y = __float_as_uint(__expf(a));
        pe[p] = o;
    }
}

// ---------------- per-dst aggregate: grid-stride, quarter-wave edge split, fused BN partials --
// Single-hop chain: pe record (coalesced, cache-warm) -> xs gather -> FMA.
// 16 lanes per edge, u16x8 (16B) per lane; main loop 16 edges/pass (4 gathers/lane in
// flight); remainder is ONE masked 16-slot pass so tails keep MLP up to 4.
template<int COLS>
__global__ void k_aggregate(const int* __restrict__ rp, const uint2* __restrict__ pe,
                            const unsigned short* __restrict__ xs, float* __restrict__ out,
                            float* __restrict__ psum, float* __restrict__ psq)
{
    __shared__ float sS[4 * 128], sQ[4 * 128];
    int wv = threadIdx.x >> 6;
    int lane = threadIdx.x & 63;
    int q = lane >> 4;               // quarter 0..3 -> edge slot
    int ql = lane & 15;
    int col = ql * 8;
    bool act = (col < COLS);
    float bs[8] = {0.f,0.f,0.f,0.f,0.f,0.f,0.f,0.f};
    float bq[8] = {0.f,0.f,0.f,0.f,0.f,0.f,0.f,0.f};

    for (int w = blockIdx.x * 4 + wv; w < NN; w += AGG_NBLK * 4) {
        int beg = rp[w], end = rp[w + 1];
        float acc[8] = {0.f,0.f,0.f,0.f,0.f,0.f,0.f,0.f};
        float den = 0.f;
        int j = beg;
        // 16 edges/pass: 4 independent gathers in flight per lane
        for (; j + 16 <= end; j += 16) {
            uint2 r0 = pe[j + q];
            uint2 r1 = pe[j + 4 + q];
            uint2 r2 = pe[j + 8 + q];
            uint2 r3 = pe[j + 12 + q];
            float e0 = __uint_as_float(r0.y);
            float e1 = __uint_as_float(r1.y);
            float e2 = __uint_as_float(r2.y);
            float e3 = __uint_as_float(r3.y);
            den += (e0 + e1) + (e2 + e3);
            if (act) {
                u16x8 u0 = *reinterpret_cast<const u16x8*>(xs + (size_t)r0.x * COLS + col);
                u16x8 u1 = *reinterpret_cast<const u16x8*>(xs + (size_t)r1.x * COLS + col);
                u16x8 u2 = *reinterpret_cast<const u16x8*>(xs + (size_t)r2.x * COLS + col);
                u16x8 u3 = *reinterpret_cast<const u16x8*>(xs + (size_t)r3.x * COLS + col);
                #pragma unroll
                for (int k = 0; k < 8; ++k)
                    acc[k] += (e0 * bf2f(u0[k]) + e1 * bf2f(u1[k]))
                            + (e2 * bf2f(u2[k]) + e3 * bf2f(u3[k]));
            }
        }
        // remainder: ONE masked 16-slot pass (slot validity is quarter-uniform)
        if (j < end) {
            int jq = j + q;
            bool v0 = jq      < end;
            bool v1 = jq + 4  < end;
            bool v2 = jq + 8  < end;
            bool v3 = jq + 12 < end;
            uint2 r0 = v0 ? pe[jq]      : uint2{0u, 0u};
            uint2 r1 = v1 ? pe[jq + 4]  : uint2{0u, 0u};
            uint2 r2 = v2 ? pe[jq + 8]  : uint2{0u, 0u};
            uint2 r3 = v3 ? pe[jq + 12] : uint2{0u, 0u};
            float e0 = __uint_as_float(r0.y);
            float e1 = __uint_as_float(r1.y);
            float e2 = __uint_as_float(r2.y);
            float e3 = __uint_as_float(r3.y);
            den += (e0 + e1) + (e2 + e3);
            if (act) {
                u16x8 u0, u1, u2, u3;
                if (v0) u0 = *reinterpret_cast<const u16x8*>(xs + (size_t)r0.x * COLS + col);
                if (v1) u1 = *reinterpret_cast<const u16x8*>(xs + (size_t)r1.x * COLS + col);
                if (v2) u2 = *reinterpret_cast<const u16x8*>(xs + (size_t)r2.x * COLS + col);
                if (v3) u3 = *reinterpret_cast<const u16x8*>(xs + (size_t)r3.x * COLS + col);
                if (v0) {
                    #pragma unroll
                    for (int k = 0; k < 8; ++k) acc[k] += e0 * bf2f(u0[k]);
                }
                if (v1) {
                    #pragma unroll
                    for (int k = 0; k < 8; ++k) acc[k] += e1 * bf2f(u1[k]);
                }
                if (v2) {
                    #pragma unroll
                    for (int k = 0; k < 8; ++k) acc[k] += e2 * bf2f(u2[k]);
                }
                if (v3) {
                    #pragma unroll
                    for (int k = 0; k < 8; ++k) acc[k] += e3 * bf2f(u3[k]);
                }
            }
        }
        #pragma unroll
        for (int k = 0; k < 8; ++k) {
            acc[k] += __shfl_xor(acc[k], 16);
            acc[k] += __shfl_xor(acc[k], 32);
        }
        den += __shfl_xor(den, 16);
        den += __shfl_xor(den, 32);
        float inv = (end > beg) ? 1.f / den : 0.f;
        if (q == 0 && act) {
            float o[8];
            #pragma unroll
            for (int k = 0; k < 8; ++k) {
                o[k] = acc[k] * inv;
                bs[k] += o[k];
                bq[k] += o[k] * o[k];
            }
            f32x4 o0 = {o[0], o[1], o[2], o[3]};
            f32x4 o1 = {o[4], o[5], o[6], o[7]};
            __builtin_nontemporal_store(o0, reinterpret_cast<f32x4*>(out + (size_t)w * COLS + col));
            __builtin_nontemporal_store(o1, reinterpret_cast<f32x4*>(out + (size_t)w * COLS + col + 4));
        }
    }
    // fold BN partials across the block's 4 waves
    if (q == 0) {
        #pragma unroll
        for (int k = 0; k < 8; ++k) {
            sS[wv * 128 + col + k] = bs[k];
            sQ[wv * 128 + col + k] = bq[k];
        }
    }
    __syncthreads();
    int t = threadIdx.x;
    if (t < 128) {
        psum[(size_t)blockIdx.x * 128 + t] = sS[t] + sS[128 + t] + sS[256 + t] + sS[384 + t];
        psq [(size_t)blockIdx.x * 128 + t] = sQ[t] + sQ[128 + t] + sQ[256 + t] + sQ[384 + t];
    }
}

// ---------------- BN stats stage 2: reduce AGG_NBLK partials (lightly-contended atomics) ----
__global__ void k_bn_stats2(const float* __restrict__ psum, const float* __restrict__ psq,
                            float* __restrict__ sums, float* __restrict__ sqs)
{
    int t = threadIdx.x;
    int c = t & 127;
    constexpr int ROWS = AGG_NBLK / 128;    // 32
    const float* sp = (t < 128) ? psum : psq;
    float s = 0.f;
    #pragma unroll 4
    for (int i = 0; i < ROWS; ++i)
        s += sp[(size_t)(blockIdx.x * ROWS + i) * 128 + c];
    unsafeAtomicAdd(((t < 128) ? sums : sqs) + c, s);
}

// ---------------- batchnorm apply (final layer -> d_out) ----------------
template<int COLS>
__global__ void k_bn_apply(const float* __restrict__ in, float* __restrict__ out,
                           const float* __restrict__ sums, const float* __restrict__ sqs,
                           const float* __restrict__ gamma, const float* __restrict__ beta,
                           int n)
{
    int idx = blockIdx.x * blockDim.x + threadIdx.x;
    if (idx >= n * COLS) return;
    int c = idx % COLS;
    float invn = 1.0f / (float)n;
    float mean = sums[c] * invn;
    float var  = sqs[c] * invn - mean * mean;     // biased, matches jnp var
    float sc = gamma[c] * rsqrtf(var + 1e-5f);
    float sh = beta[c] - mean * sc;
    out[idx] = in[idx] * sc + sh;
}

extern "C" void kernel_launch(void* const* d_in, const int* in_sizes, int n_in,
                              void* d_out, int out_size, void* d_ws, size_t ws_size,
                              hipStream_t stream)
{
    const float* x    = (const float*)d_in[0];
    const int*   eidx = (const int*)d_in[1];
    const float* eatt = (const float*)d_in[2];
    const float* W0   = (const float*)d_in[3];
    const float* as0  = (const float*)d_in[4];
    const float* ad0  = (const float*)d_in[5];
    const float* We0  = (const float*)d_in[6];
    const float* ae0  = (const float*)d_in[7];
    // d_in[8] = b0 : cancels through BN
    const float* W1   = (const float*)d_in[9];
    const float* as1  = (const float*)d_in[10];
    const float* ad1  = (const float*)d_in[11];
    const float* We1  = (const float*)d_in[12];
    const float* ae1  = (const float*)d_in[13];
    // d_in[14] = b1 : cancels through BN
    const float* bng  = (const float*)d_in[15];
    const float* bnb  = (const float*)d_in[16];
    const float* bnfg = (const float*)d_in[17];
    const float* bnfb = (const float*)d_in[18];

    const int N = NN, E = NE;
    const int* src = eidx;
    const int* dst = eidx + E;

    float* ws = (float*)d_ws;
    size_t off = 0;
    unsigned short* xs0b = (unsigned short*)(ws + off); off += (size_t)N * 64;   // N*128 bf16
    float* h   = ws + off;      off += (size_t)N * 128;                          // fp32 25.6MB
    unsigned short* xs1b = (unsigned short*)(ws + off); off += (size_t)N * 56;   // N*112 bf16
    uint2* pack = (uint2*)(ws + off);   off += (size_t)E * 2;                    // 8B/edge
    int*   rp   = (int*)(ws + off);     off += N + 2;
    int*   rank = (int*)(ws + off);     off += E;                                // per-edge rank
    int*   deg  = (int*)(ws + off);     off += N;
    float* als0 = ws + off;     off += N;
    float* ald0 = ws + off;     off += N;
    float* als1 = ws + off;     off += N;
    float* ald1 = ws + off;     off += N;
    float* stats = ws + off;    off += 512;
    float* ve = ws + off;       off += 16;
    int*   partial = (int*)(ws + off);  off += SCAN_NBLK;
    float* psum = ws + off;     off += (size_t)AGG_NBLK * 128;
    float* psq  = ws + off;     off += (size_t)AGG_NBLK * 128;
    unsigned short* Wth0 = (unsigned short*)(ws + off); off += 128 * 64;         // 128x128 bf16
    unsigned short* Wtl0 = (unsigned short*)(ws + off); off += 128 * 64;
    unsigned short* Wth1 = (unsigned short*)(ws + off); off += 112 * 64;         // 112x128 bf16
    unsigned short* Wtl1 = (unsigned short*)(ws + off); off += 112 * 64;
    float* out1 = h;            // alias: h (fp32) dead after layer-1 gemm consumes it

    // pe: per-edge {src, exp(alpha)} records, 6.4MB. Carved out of d_out (22.4MB),
    // which is dead until k_bn_apply fully overwrites it at the end.
    uint2* pe = (uint2*)d_out;

    float* sum0 = stats;
    float* sq0  = stats + 128;
    float* sum1 = stats + 256;
    float* sq1  = stats + 384;

    // ---- init (ws poisoned 0xAA before every call) ----
    k_init_cvt<<<(N + 255) / 256, 256, 0, stream>>>(deg, stats, We0, ae0, We1, ae1, ve,
                                                    W0, W1, Wth0, Wtl0, Wth1, Wtl1);

    // ---- CSR build: deg(+rank) -> scan -> atomic-free fill ----
    k_deg<<<(E + 255) / 256, 256, 0, stream>>>(dst, deg, rank, E);
    k_scan1<<<SCAN_NBLK, SCAN_B, 0, stream>>>(deg, partial);
    k_scan3<<<SCAN_NBLK, SCAN_B, 0, stream>>>(deg, partial, rp);
    k_csr_fill<<<(E + 255) / 256, 256, 0, stream>>>(src, dst, eatt, ve, rp, rank, pack, E);

    // ---- layer 0: 128 -> 128 ----
    k_gemm_mfma<128, false><<<NPAD / 64, 256, 0, stream>>>(x, Wth0, Wtl0, xs0b,
                                                           as0, ad0, als0, ald0,
                                                           nullptr, nullptr, nullptr, nullptr);
    k_logit<0><<<(N + 15) / 16, 256, 0, stream>>>(rp, pack, als0, ald0, pe);
    k_aggregate<128><<<AGG_NBLK, 256, 0, stream>>>(rp, pe, xs0b, h, psum, psq);
    k_bn_stats2<<<128, 256, 0, stream>>>(psum, psq, sum0, sq0);

    // ---- layer 1: 128 -> 112 (BN0+ReLU fused into GEMM A-load) ----
    k_gemm_mfma<112, true><<<NPAD / 64, 256, 0, stream>>>(h, Wth1, Wtl1, xs1b,
                                                          as1, ad1, als1, ald1,
                                                          sum0, sq0, bng, bnb);
    k_logit<1><<<(N + 15) / 16, 256, 0, stream>>>(rp, pack, als1, ald1, pe);
    k_aggregate<112><<<AGG_NBLK, 256, 0, stream>>>(rp, pe, xs1b, out1, psum, psq);
    k_bn_stats2<<<128, 256, 0, stream>>>(psum, psq, sum1, sq1);
    k_bn_apply<112><<<(N * 112 + 255) / 256, 256, 0, stream>>>(out1, (float*)d_out, sum1, sq1, bnfg, bnfb, N);
}

// Round 3
// 376.124 us; speedup vs baseline: 1.1051x; 1.0274x over previous
//
#include <hip/hip_runtime.h>
#include <math.h>

// GAT 2-layer: N=50000 nodes, E=800000 edges, heads=1
// dims: 128 -> 128 (BN+ReLU) -> 112 (BN)
#define NN 50000
#define NPAD 50048               // 782 * 64, MFMA row tiles
#define NE 800000
#define SCAN_B 256
#define SCAN_NBLK ((NN + SCAN_B - 1) / SCAN_B)   // 196
#define AGG_NBLK 2048            // 2048 blocks * 16 quarters = 32768 node slots

typedef __attribute__((ext_vector_type(8))) short bf16x8;           // MFMA A/B frag
typedef __attribute__((ext_vector_type(4))) float f32x4;            // MFMA C/D frag
typedef __attribute__((ext_vector_type(8))) unsigned short u16x8;   // 16B gather

__device__ __forceinline__ unsigned short f2bf(float x) {
    unsigned u = __float_as_uint(x);
    u += 0x7fffu + ((u >> 16) & 1);              // round-to-nearest-even
    return (unsigned short)(u >> 16);
}
__device__ __forceinline__ float bf2f(unsigned short h) {
    return __uint_as_float(((unsigned)h) << 16);
}

// ---------------- init: deg/stats zero + ve fold + W split-transpose ----------------
// ve[0..7] = We0 @ a_edge0 ; ve[8..15] = We1 @ a_edge1   (heads=1 folding)
__global__ void k_init_cvt(int* __restrict__ deg, float* __restrict__ stats,
                           const float* __restrict__ We0, const float* __restrict__ ae0,
                           const float* __restrict__ We1, const float* __restrict__ ae1,
                           float* __restrict__ ve,
                           const float* __restrict__ W0, const float* __restrict__ W1,
                           unsigned short* __restrict__ Wth0, unsigned short* __restrict__ Wtl0,
                           unsigned short* __restrict__ Wth1, unsigned short* __restrict__ Wtl1)
{
    int idx = blockIdx.x * 256 + threadIdx.x;
    if (idx < NN) deg[idx] = 0;
    if (idx < 512) stats[idx] = 0.f;
    if (idx < 128 * 128) {
        int k = idx / 128, c = idx % 128;
        float v = W0[idx];
        unsigned short hi = f2bf(v);
        Wth0[c * 128 + k] = hi;
        Wtl0[c * 128 + k] = f2bf(v - bf2f(hi));
    } else if (idx < 128 * 128 + 128 * 112) {
        int i2 = idx - 128 * 128;
        int k = i2 / 112, c = i2 % 112;
        float v = W1[i2];
        unsigned short hi = f2bf(v);
        Wth1[c * 128 + k] = hi;
        Wtl1[c * 128 + k] = f2bf(v - bf2f(hi));
    }
    if (blockIdx.x == gridDim.x - 1) {
        int j = threadIdx.x;
        if (j < 8) {
            float s = 0.f;
            for (int c = 0; c < 128; ++c) s += We0[j * 128 + c] * ae0[c];
            ve[j] = s;
        } else if (j < 16) {
            int jj = j - 8;
            float s = 0.f;
            for (int c = 0; c < 112; ++c) s += We1[jj * 112 + c] * ae1[c];
            ve[8 + jj] = s;
        }
    }
}

// ---------------- CSR build ----------------
// rank[e] = old count of dst -> position of e within its segment. Free by-product
// of the degree count; removes the atomic round-trip from the fill kernel.
__global__ void k_deg(const int* __restrict__ dst, int* __restrict__ deg,
                      int* __restrict__ rank, int E_)
{
    int e = blockIdx.x * blockDim.x + threadIdx.x;
    if (e < E_) rank[e] = atomicAdd(&deg[dst[e]], 1);
}

__global__ void k_scan1(const int* __restrict__ deg, int* __restrict__ partial)
{
    __shared__ int sm[SCAN_B];
    int t = threadIdx.x;
    int idx = blockIdx.x * SCAN_B + t;
    sm[t] = (idx < NN) ? deg[idx] : 0;
    __syncthreads();
    #pragma unroll
    for (int off = SCAN_B / 2; off > 0; off >>= 1) {
        if (t < off) sm[t] += sm[t + off];
        __syncthreads();
    }
    if (t == 0) partial[blockIdx.x] = sm[0];
}

// fused stage 2+3: each block computes its own prefix over partials, then local scan
__global__ void k_scan3(const int* __restrict__ deg, const int* __restrict__ partial,
                        int* __restrict__ rp)
{
    __shared__ int sm[SCAN_B];
    __shared__ int pbase;
    int t = threadIdx.x;
    int pv = (t < SCAN_NBLK && t < blockIdx.x) ? partial[t] : 0;
    sm[t] = pv;
    __syncthreads();
    #pragma unroll
    for (int off = SCAN_B / 2; off > 0; off >>= 1) {
        if (t < off) sm[t] += sm[t + off];
        __syncthreads();
    }
    if (t == 0) pbase = sm[0];
    __syncthreads();
    int idx = blockIdx.x * SCAN_B + t;
    int v = (idx < NN) ? deg[idx] : 0;
    sm[t] = v;
    __syncthreads();
    #pragma unroll
    for (int off = 1; off < SCAN_B; off <<= 1) {
        int u = (t >= off) ? sm[t - off] : 0;
        __syncthreads();
        sm[t] += u;
        __syncthreads();
    }
    int excl = pbase + ((t == 0) ? 0 : sm[t - 1]);
    if (idx < NN) rp[idx] = excl;
    if (idx == NN - 1) rp[NN] = excl + v;
}

// ---------------- edge pack + layer-0 logit: 16B records {src, ex0_f32, a1_f32, 0} ----------
// Runs AFTER gemm0, so it folds the layer-0 logit+exp here (src/dst already loaded ->
// als0/ald0 gathers are nearly free, hidden under the scatter-store latency).
// pos = rp[dst] + rank  (precomputed) -> scatter store is fire-and-forget, no atomic.
__global__ void k_csr_fill_l0(const int* __restrict__ src, const int* __restrict__ dst,
                              const float* __restrict__ eatt, const float* __restrict__ ve,
                              const int* __restrict__ rp, const int* __restrict__ rank,
                              const float* __restrict__ als, const float* __restrict__ ald,
                              uint4* __restrict__ pk, int E_)
{
    int e = blockIdx.x * blockDim.x + threadIdx.x;
    if (e >= E_) return;
    const float4* ea = reinterpret_cast<const float4*>(eatt + (size_t)e * 8);
    float4 e0 = ea[0], e1 = ea[1];
    float a0 = e0.x * ve[0] + e0.y * ve[1] + e0.z * ve[2] + e0.w * ve[3]
             + e1.x * ve[4] + e1.y * ve[5] + e1.z * ve[6] + e1.w * ve[7];
    float a1 = e0.x * ve[8] + e0.y * ve[9] + e0.z * ve[10] + e0.w * ve[11]
             + e1.x * ve[12] + e1.y * ve[13] + e1.z * ve[14] + e1.w * ve[15];
    int s = src[e], d = dst[e];
    float av = als[s] + ald[d] + a0;
    av = av > 0.f ? av : 0.2f * av;
    float ex0 = __expf(av);
    int pos = rp[d] + rank[e];
    uint4 rec;
    rec.x = (unsigned)s;
    rec.y = __float_as_uint(ex0);
    rec.z = __float_as_uint(a1);
    rec.w = 0u;
    pk[pos] = rec;
}

// ---------------- MFMA GEMM: one wave = 16 rows x COLS, bf16x3 split precision ----------------
template<int COLS, bool BN_IN>
__global__ void k_gemm_mfma(const float* __restrict__ A,
                            const unsigned short* __restrict__ Wth,
                            const unsigned short* __restrict__ Wtl,
                            unsigned short* __restrict__ out,
                            const float* __restrict__ a_src, const float* __restrict__ a_dst,
                            float* __restrict__ als, float* __restrict__ ald,
                            const float* __restrict__ bsum, const float* __restrict__ bsq,
                            const float* __restrict__ gamma, const float* __restrict__ beta)
{
    constexpr int NT = COLS / 16;
    __shared__ float scN[128], shN[128];
    if (BN_IN) {
        if (threadIdx.x < 128) {
            int k = threadIdx.x;
            float invn = 1.0f / (float)NN;
            float mean = bsum[k] * invn;
            float var  = bsq[k] * invn - mean * mean;
            float sc = gamma[k] * rsqrtf(var + 1e-5f);
            scN[k] = sc;
            shN[k] = beta[k] - mean * sc;
        }
        __syncthreads();
    }
    int wv = threadIdx.x >> 6;
    int lane = threadIdx.x & 63;
    int r0 = blockIdx.x * 64 + wv * 16;
    int m = lane & 15;
    int quad = lane >> 4;
    int arow = r0 + m;
    int rc = (arow < NN) ? arow : NN - 1;    // clamp: pad rows computed but never stored
    const float* pa = A + (size_t)rc * 128 + quad * 8;

    f32x4 acc[NT];
    #pragma unroll
    for (int t = 0; t < NT; ++t) acc[t] = f32x4{0.f, 0.f, 0.f, 0.f};

    #pragma unroll
    for (int ks = 0; ks < 4; ++ks) {
        float4 v0 = *reinterpret_cast<const float4*>(pa + ks * 32);
        float4 v1 = *reinterpret_cast<const float4*>(pa + ks * 32 + 4);
        float vv[8] = {v0.x, v0.y, v0.z, v0.w, v1.x, v1.y, v1.z, v1.w};
        int kb = ks * 32 + quad * 8;
        bf16x8 ah, al;
        #pragma unroll
        for (int jj = 0; jj < 8; ++jj) {
            float f = vv[jj];
            if (BN_IN) f = fmaxf(f * scN[kb + jj] + shN[kb + jj], 0.f);
            unsigned short hi = f2bf(f);
            ah[jj] = (short)hi;
            al[jj] = (short)f2bf(f - bf2f(hi));
        }
        #pragma unroll
        for (int t = 0; t < NT; ++t) {
            size_t boff = (size_t)(t * 16 + m) * 128 + ks * 32 + quad * 8;
            bf16x8 bh = *reinterpret_cast<const bf16x8*>(Wth + boff);
            bf16x8 bl = *reinterpret_cast<const bf16x8*>(Wtl + boff);
            acc[t] = __builtin_amdgcn_mfma_f32_16x16x32_bf16(ah, bh, acc[t], 0, 0, 0);
            acc[t] = __builtin_amdgcn_mfma_f32_16x16x32_bf16(al, bh, acc[t], 0, 0, 0);
            acc[t] = __builtin_amdgcn_mfma_f32_16x16x32_bf16(ah, bl, acc[t], 0, 0, 0);
        }
    }

    // epilogue: bf16 store + fused attention dots (C/D: col=lane&15, row=quad*4+reg)
    float p[4] = {0.f, 0.f, 0.f, 0.f}, q[4] = {0.f, 0.f, 0.f, 0.f};
    #pragma unroll
    for (int t = 0; t < NT; ++t) {
        int c = t * 16 + m;
        float asv = a_src[c], adv = a_dst[c];
        #pragma unroll
        for (int rI = 0; rI < 4; ++rI) {
            float v = acc[t][rI];
            int row = r0 + quad * 4 + rI;
            if (row < NN) out[(size_t)row * COLS + c] = f2bf(v);
            p[rI] += v * asv;
            q[rI] += v * adv;
        }
    }
    #pragma unroll
    for (int rI = 0; rI < 4; ++rI) {
        #pragma unroll
        for (int off = 1; off <= 8; off <<= 1) {
            p[rI] += __shfl_xor(p[rI], off);
            q[rI] += __shfl_xor(q[rI], off);
        }
    }
    if (m == 0) {
        #pragma unroll
        for (int rI = 0; rI < 4; ++rI) {
            int row = r0 + quad * 4 + rI;
            if (row < NN) { als[row] = p[rI]; ald[row] = q[rI]; }
        }
    }
}

// ---------------- layer-1 logit+exp: quarter-per-node, coalesced 16B reads -> 8B writes -----
__global__ void k_logit1(const int* __restrict__ rp, const uint4* __restrict__ pk,
                         const float* __restrict__ als, const float* __restrict__ ald,
                         uint2* __restrict__ pe)
{
    int ql = threadIdx.x & 15;
    int w = blockIdx.x * 16 + (threadIdx.x >> 4);
    if (w >= NN) return;
    int beg = rp[w], end = rp[w + 1];
    float aldv = ald[w];
    for (int p = beg + ql; p < end; p += 16) {
        uint4 r = pk[p];
        float a = als[r.x] + aldv + __uint_as_float(r.z);
        a = a > 0.f ? a : 0.2f * a;
        uint2 o;
        o.x = r.x;
        o.y = __float_as_uint(__expf(a));
        pe[p] = o;
    }
}

// ---------------- aggregate: QUARTER-PER-NODE, zero shuffles, fused BN partials -------------
// 16 lanes own one node's full row (16 x 8 cols). pe records are broadcast to the quarter;
// den is replicated per-lane (no reduce). 4 gathers in flight per lane; the 4 quarters of a
// wave advance through independent nodes, so segment-end drains don't stall the wave.
// RSTRIDE: pe record stride in uint2 units (2 for layer-0's 16B records, 1 for layer-1's 8B).
template<int COLS, int RSTRIDE>
__global__ void k_aggregate(const int* __restrict__ rp, const uint2* __restrict__ pe,
                            const unsigned short* __restrict__ xs, float* __restrict__ out,
                            float* __restrict__ psum, float* __restrict__ psq)
{
    __shared__ float sS[16 * 128], sQ[16 * 128];
    int ql = threadIdx.x & 15;
    int wq = threadIdx.x >> 4;               // 0..15 quarter slot within block
    int col = ql * 8;
    bool act = (col < COLS);
    int qid = blockIdx.x * 16 + wq;          // global quarter = node slot
    float bs[8] = {0.f,0.f,0.f,0.f,0.f,0.f,0.f,0.f};
    float bq[8] = {0.f,0.f,0.f,0.f,0.f,0.f,0.f,0.f};

    for (int w = qid; w < NN; w += AGG_NBLK * 16) {
        int beg = rp[w], end = rp[w + 1];
        float acc[8] = {0.f,0.f,0.f,0.f,0.f,0.f,0.f,0.f};
        float den = 0.f;
        int j = beg;
        // 4 edges/pass, 4 independent gathers in flight per lane
        for (; j + 4 <= end; j += 4) {
            uint2 r0 = pe[(size_t)(j    ) * RSTRIDE];
            uint2 r1 = pe[(size_t)(j + 1) * RSTRIDE];
            uint2 r2 = pe[(size_t)(j + 2) * RSTRIDE];
            uint2 r3 = pe[(size_t)(j + 3) * RSTRIDE];
            float e0 = __uint_as_float(r0.y);
            float e1 = __uint_as_float(r1.y);
            float e2 = __uint_as_float(r2.y);
            float e3 = __uint_as_float(r3.y);
            den += (e0 + e1) + (e2 + e3);
            if (act) {
                u16x8 u0 = *reinterpret_cast<const u16x8*>(xs + (size_t)r0.x * COLS + col);
                u16x8 u1 = *reinterpret_cast<const u16x8*>(xs + (size_t)r1.x * COLS + col);
                u16x8 u2 = *reinterpret_cast<const u16x8*>(xs + (size_t)r2.x * COLS + col);
                u16x8 u3 = *reinterpret_cast<const u16x8*>(xs + (size_t)r3.x * COLS + col);
                #pragma unroll
                for (int k = 0; k < 8; ++k)
                    acc[k] += (e0 * bf2f(u0[k]) + e1 * bf2f(u1[k]))
                            + (e2 * bf2f(u2[k]) + e3 * bf2f(u3[k]));
            }
        }
        // tail: one masked 4-slot pass (slot validity uniform across the quarter)
        if (j < end) {
            bool v1 = j + 1 < end;
            bool v2 = j + 2 < end;
            bool v3 = j + 3 < end;
            uint2 r0 = pe[(size_t)j * RSTRIDE];
            uint2 r1 = v1 ? pe[(size_t)(j + 1) * RSTRIDE] : uint2{0u, 0u};
            uint2 r2 = v2 ? pe[(size_t)(j + 2) * RSTRIDE] : uint2{0u, 0u};
            uint2 r3 = v3 ? pe[(size_t)(j + 3) * RSTRIDE] : uint2{0u, 0u};
            float e0 = __uint_as_float(r0.y);
            float e1 = __uint_as_float(r1.y);
            float e2 = __uint_as_float(r2.y);
            float e3 = __uint_as_float(r3.y);
            den += (e0 + e1) + (e2 + e3);
            if (act) {
                u16x8 u0 = *reinterpret_cast<const u16x8*>(xs + (size_t)r0.x * COLS + col);
                #pragma unroll
                for (int k = 0; k < 8; ++k) acc[k] += e0 * bf2f(u0[k]);
                if (v1) {
                    u16x8 u1 = *reinterpret_cast<const u16x8*>(xs + (size_t)r1.x * COLS + col);
                    #pragma unroll
                    for (int k = 0; k < 8; ++k) acc[k] += e1 * bf2f(u1[k]);
                }
                if (v2) {
                    u16x8 u2 = *reinterpret_cast<const u16x8*>(xs + (size_t)r2.x * COLS + col);
                    #pragma unroll
                    for (int k = 0; k < 8; ++k) acc[k] += e2 * bf2f(u2[k]);
                }
                if (v3) {
                    u16x8 u3 = *reinterpret_cast<const u16x8*>(xs + (size_t)r3.x * COLS + col);
                    #pragma unroll
                    for (int k = 0; k < 8; ++k) acc[k] += e3 * bf2f(u3[k]);
                }
            }
        }
        float inv = (end > beg) ? 1.f / den : 0.f;
        if (act) {
            float o[8];
            #pragma unroll
            for (int k = 0; k < 8; ++k) {
                o[k] = acc[k] * inv;
                bs[k] += o[k];
                bq[k] += o[k] * o[k];
            }
            f32x4 o0 = {o[0], o[1], o[2], o[3]};
            f32x4 o1 = {o[4], o[5], o[6], o[7]};
            __builtin_nontemporal_store(o0, reinterpret_cast<f32x4*>(out + (size_t)w * COLS + col));
            __builtin_nontemporal_store(o1, reinterpret_cast<f32x4*>(out + (size_t)w * COLS + col + 4));
        }
    }
    // fold BN partials across the block's 16 quarters (once per kernel)
    #pragma unroll
    for (int k = 0; k < 8; ++k) {
        sS[wq * 128 + col + k] = act ? bs[k] : 0.f;
        sQ[wq * 128 + col + k] = act ? bq[k] : 0.f;
    }
    __syncthreads();
    int t = threadIdx.x;
    if (t < 128) {
        float s = 0.f, s2 = 0.f;
        #pragma unroll
        for (int r = 0; r < 16; ++r) { s += sS[r * 128 + t]; s2 += sQ[r * 128 + t]; }
        psum[(size_t)blockIdx.x * 128 + t] = s;
        psq [(size_t)blockIdx.x * 128 + t] = s2;
    }
}

// ---------------- BN stats stage 2: reduce AGG_NBLK partials (lightly-contended atomics) ----
__global__ void k_bn_stats2(const float* __restrict__ psum, const float* __restrict__ psq,
                            float* __restrict__ sums, float* __restrict__ sqs)
{
    int t = threadIdx.x;
    int c = t & 127;
    constexpr int ROWS = AGG_NBLK / 128;    // 16
    const float* sp = (t < 128) ? psum : psq;
    float s = 0.f;
    #pragma unroll 4
    for (int i = 0; i < ROWS; ++i)
        s += sp[(size_t)(blockIdx.x * ROWS + i) * 128 + c];
    unsafeAtomicAdd(((t < 128) ? sums : sqs) + c, s);
}

// ---------------- batchnorm apply (final layer -> d_out) ----------------
template<int COLS>
__global__ void k_bn_apply(const float* __restrict__ in, float* __restrict__ out,
                           const float* __restrict__ sums, const float* __restrict__ sqs,
                           const float* __restrict__ gamma, const float* __restrict__ beta,
                           int n)
{
    int idx = blockIdx.x * blockDim.x + threadIdx.x;
    if (idx >= n * COLS) return;
    int c = idx % COLS;
    float invn = 1.0f / (float)n;
    float mean = sums[c] * invn;
    float var  = sqs[c] * invn - mean * mean;     // biased, matches jnp var
    float sc = gamma[c] * rsqrtf(var + 1e-5f);
    float sh = beta[c] - mean * sc;
    out[idx] = in[idx] * sc + sh;
}

extern "C" void kernel_launch(void* const* d_in, const int* in_sizes, int n_in,
                              void* d_out, int out_size, void* d_ws, size_t ws_size,
                              hipStream_t stream)
{
    const float* x    = (const float*)d_in[0];
    const int*   eidx = (const int*)d_in[1];
    const float* eatt = (const float*)d_in[2];
    const float* W0   = (const float*)d_in[3];
    const float* as0  = (const float*)d_in[4];
    const float* ad0  = (const float*)d_in[5];
    const float* We0  = (const float*)d_in[6];
    const float* ae0  = (const float*)d_in[7];
    // d_in[8] = b0 : cancels through BN
    const float* W1   = (const float*)d_in[9];
    const float* as1  = (const float*)d_in[10];
    const float* ad1  = (const float*)d_in[11];
    const float* We1  = (const float*)d_in[12];
    const float* ae1  = (const float*)d_in[13];
    // d_in[14] = b1 : cancels through BN
    const float* bng  = (const float*)d_in[15];
    const float* bnb  = (const float*)d_in[16];
    const float* bnfg = (const float*)d_in[17];
    const float* bnfb = (const float*)d_in[18];

    const int N = NN, E = NE;
    const int* src = eidx;
    const int* dst = eidx + E;

    float* ws = (float*)d_ws;
    size_t off = 0;
    unsigned short* xs0b = (unsigned short*)(ws + off); off += (size_t)N * 64;   // N*128 bf16
    float* h   = ws + off;      off += (size_t)N * 128;                          // fp32 25.6MB
    unsigned short* xs1b = (unsigned short*)(ws + off); off += (size_t)N * 56;   // N*112 bf16
    int*   rp   = (int*)(ws + off);     off += N + 2;
    int*   rank = (int*)(ws + off);     off += E;                                // per-edge rank
    int*   deg  = (int*)(ws + off);     off += N;
    float* als0 = ws + off;     off += N;
    float* ald0 = ws + off;     off += N;
    float* als1 = ws + off;     off += N;
    float* ald1 = ws + off;     off += N;
    float* stats = ws + off;    off += 512;
    float* ve = ws + off;       off += 16;
    int*   partial = (int*)(ws + off);  off += SCAN_NBLK;
    float* psum = ws + off;     off += (size_t)AGG_NBLK * 128;
    float* psq  = ws + off;     off += (size_t)AGG_NBLK * 128;
    unsigned short* Wth0 = (unsigned short*)(ws + off); off += 128 * 64;         // 128x128 bf16
    unsigned short* Wtl0 = (unsigned short*)(ws + off); off += 128 * 64;
    unsigned short* Wth1 = (unsigned short*)(ws + off); off += 112 * 64;         // 112x128 bf16
    unsigned short* Wtl1 = (unsigned short*)(ws + off); off += 112 * 64;
    float* out1 = h;            // alias: h (fp32) dead after layer-1 gemm consumes it

    // pk: 16B/edge records {src, ex0, a1_f32, 0} = 12.8MB, carved from d_out (22.4MB,
    // dead until k_bn_apply overwrites it). pe1: 8B/edge {src, ex1} right after (6.4MB).
    uint4* pk  = (uint4*)d_out;
    uint2* pe1 = (uint2*)((char*)d_out + (size_t)E * 16);

    float* sum0 = stats;
    float* sq0  = stats + 128;
    float* sum1 = stats + 256;
    float* sq1  = stats + 384;

    // ---- init (ws poisoned 0xAA before every call) ----
    k_init_cvt<<<(N + 255) / 256, 256, 0, stream>>>(deg, stats, We0, ae0, We1, ae1, ve,
                                                    W0, W1, Wth0, Wtl0, Wth1, Wtl1);

    // ---- CSR build: deg(+rank) -> scan ----
    k_deg<<<(E + 255) / 256, 256, 0, stream>>>(dst, deg, rank, E);
    k_scan1<<<SCAN_NBLK, SCAN_B, 0, stream>>>(deg, partial);
    k_scan3<<<SCAN_NBLK, SCAN_B, 0, stream>>>(deg, partial, rp);

    // ---- layer 0: 128 -> 128 (fill carries the layer-0 logit, so gemm0 runs first) ----
    k_gemm_mfma<128, false><<<NPAD / 64, 256, 0, stream>>>(x, Wth0, Wtl0, xs0b,
                                                           as0, ad0, als0, ald0,
                                                           nullptr, nullptr, nullptr, nullptr);
    k_csr_fill_l0<<<(E + 255) / 256, 256, 0, stream>>>(src, dst, eatt, ve, rp, rank,
                                                       als0, ald0, pk, E);
    k_aggregate<128, 2><<<AGG_NBLK, 256, 0, stream>>>(rp, (const uint2*)pk, xs0b, h, psum, psq);
    k_bn_stats2<<<128, 256, 0, stream>>>(psum, psq, sum0, sq0);

    // ---- layer 1: 128 -> 112 (BN0+ReLU fused into GEMM A-load) ----
    k_gemm_mfma<112, true><<<NPAD / 64, 256, 0, stream>>>(h, Wth1, Wtl1, xs1b,
                                                          as1, ad1, als1, ald1,
                                                          sum0, sq0, bng, bnb);
    k_logit1<<<(N + 15) / 16, 256, 0, stream>>>(rp, pk, als1, ald1, pe1);
    k_aggregate<112, 1><<<AGG_NBLK, 256, 0, stream>>>(rp, pe1, xs1b, out1, psum, psq);
    k_bn_stats2<<<128, 256, 0, stream>>>(psum, psq, sum1, sq1);
    k_bn_apply<112><<<(N * 112 + 255) / 256, 256, 0, stream>>>(out1, (float*)d_out, sum1, sq1, bnfg, bnfb, N);
}

// Round 4
// 339.770 us; speedup vs baseline: 1.2233x; 1.1070x over previous
//
#include <hip/hip_runtime.h>
#include <math.h>

// GAT 2-layer: N=50000 nodes, E=800000 edges, heads=1
// dims: 128 -> 128 (BN+ReLU) -> 112 (BN)
#define NN 50000
#define NPAD 50048               // 782 * 64, MFMA row tiles
#define NE 800000
#define SCAN_B 256
#define SCAN_NBLK ((NN + SCAN_B - 1) / SCAN_B)   // 196
#define AGG_NBLK 2048            // 2048 blocks * 16 quarters = 32768 node slots

typedef __attribute__((ext_vector_type(8))) short bf16x8;           // MFMA A/B frag
typedef __attribute__((ext_vector_type(4))) float f32x4;            // MFMA C/D frag
typedef __attribute__((ext_vector_type(8))) unsigned short u16x8;   // 16B gather

__device__ __forceinline__ unsigned short f2bf(float x) {
    unsigned u = __float_as_uint(x);
    u += 0x7fffu + ((u >> 16) & 1);              // round-to-nearest-even
    return (unsigned short)(u >> 16);
}
__device__ __forceinline__ float bf2f(unsigned short h) {
    return __uint_as_float(((unsigned)h) << 16);
}

// ---------------- init: deg/stats zero + ve fold + W split-transpose ----------------
// ve[0..7] = We0 @ a_edge0 ; ve[8..15] = We1 @ a_edge1   (heads=1 folding)
__global__ void k_init_cvt(int* __restrict__ deg, float* __restrict__ stats,
                           const float* __restrict__ We0, const float* __restrict__ ae0,
                           const float* __restrict__ We1, const float* __restrict__ ae1,
                           float* __restrict__ ve,
                           const float* __restrict__ W0, const float* __restrict__ W1,
                           unsigned short* __restrict__ Wth0, unsigned short* __restrict__ Wtl0,
                           unsigned short* __restrict__ Wth1, unsigned short* __restrict__ Wtl1)
{
    int idx = blockIdx.x * 256 + threadIdx.x;
    if (idx < NN) deg[idx] = 0;
    if (idx < 512) stats[idx] = 0.f;
    if (idx < 128 * 128) {
        int k = idx / 128, c = idx % 128;
        float v = W0[idx];
        unsigned short hi = f2bf(v);
        Wth0[c * 128 + k] = hi;
        Wtl0[c * 128 + k] = f2bf(v - bf2f(hi));
    } else if (idx < 128 * 128 + 128 * 112) {
        int i2 = idx - 128 * 128;
        int k = i2 / 112, c = i2 % 112;
        float v = W1[i2];
        unsigned short hi = f2bf(v);
        Wth1[c * 128 + k] = hi;
        Wtl1[c * 128 + k] = f2bf(v - bf2f(hi));
    }
    if (blockIdx.x == gridDim.x - 1) {
        int j = threadIdx.x;
        if (j < 8) {
            float s = 0.f;
            for (int c = 0; c < 128; ++c) s += We0[j * 128 + c] * ae0[c];
            ve[j] = s;
        } else if (j < 16) {
            int jj = j - 8;
            float s = 0.f;
            for (int c = 0; c < 112; ++c) s += We1[jj * 112 + c] * ae1[c];
            ve[8 + jj] = s;
        }
    }
}

// ---------------- CSR build ----------------
// rank[e] = old count of dst -> position of e within its segment. Free by-product
// of the degree count; removes the atomic round-trip from the fill kernel.
__global__ void k_deg(const int* __restrict__ dst, int* __restrict__ deg,
                      int* __restrict__ rank, int E_)
{
    int e = blockIdx.x * blockDim.x + threadIdx.x;
    if (e < E_) rank[e] = atomicAdd(&deg[dst[e]], 1);
}

__global__ void k_scan1(const int* __restrict__ deg, int* __restrict__ partial)
{
    __shared__ int sm[SCAN_B];
    int t = threadIdx.x;
    int idx = blockIdx.x * SCAN_B + t;
    sm[t] = (idx < NN) ? deg[idx] : 0;
    __syncthreads();
    #pragma unroll
    for (int off = SCAN_B / 2; off > 0; off >>= 1) {
        if (t < off) sm[t] += sm[t + off];
        __syncthreads();
    }
    if (t == 0) partial[blockIdx.x] = sm[0];
}

// fused stage 2+3: each block computes its own prefix over partials, then local scan
__global__ void k_scan3(const int* __restrict__ deg, const int* __restrict__ partial,
                        int* __restrict__ rp)
{
    __shared__ int sm[SCAN_B];
    __shared__ int pbase;
    int t = threadIdx.x;
    int pv = (t < SCAN_NBLK && t < blockIdx.x) ? partial[t] : 0;
    sm[t] = pv;
    __syncthreads();
    #pragma unroll
    for (int off = SCAN_B / 2; off > 0; off >>= 1) {
        if (t < off) sm[t] += sm[t + off];
        __syncthreads();
    }
    if (t == 0) pbase = sm[0];
    __syncthreads();
    int idx = blockIdx.x * SCAN_B + t;
    int v = (idx < NN) ? deg[idx] : 0;
    sm[t] = v;
    __syncthreads();
    #pragma unroll
    for (int off = 1; off < SCAN_B; off <<= 1) {
        int u = (t >= off) ? sm[t - off] : 0;
        __syncthreads();
        sm[t] += u;
        __syncthreads();
    }
    int excl = pbase + ((t == 0) ? 0 : sm[t - 1]);
    if (idx < NN) rp[idx] = excl;
    if (idx == NN - 1) rp[NN] = excl + v;
}

// ---------------- edge pack + layer-0 logit: 16B records {src, ex0_f32, a1_f32, 0} ----------
// Runs AFTER gemm0, so it folds the layer-0 logit+exp here (src/dst already loaded ->
// als0/ald0 gathers are nearly free, hidden under the scatter-store latency).
// pos = rp[dst] + rank  (precomputed) -> scatter store is fire-and-forget, no atomic.
__global__ void k_csr_fill_l0(const int* __restrict__ src, const int* __restrict__ dst,
                              const float* __restrict__ eatt, const float* __restrict__ ve,
                              const int* __restrict__ rp, const int* __restrict__ rank,
                              const float* __restrict__ als, const float* __restrict__ ald,
                              uint4* __restrict__ pk, int E_)
{
    int e = blockIdx.x * blockDim.x + threadIdx.x;
    if (e >= E_) return;
    const float4* ea = reinterpret_cast<const float4*>(eatt + (size_t)e * 8);
    float4 e0 = ea[0], e1 = ea[1];
    float a0 = e0.x * ve[0] + e0.y * ve[1] + e0.z * ve[2] + e0.w * ve[3]
             + e1.x * ve[4] + e1.y * ve[5] + e1.z * ve[6] + e1.w * ve[7];
    float a1 = e0.x * ve[8] + e0.y * ve[9] + e0.z * ve[10] + e0.w * ve[11]
             + e1.x * ve[12] + e1.y * ve[13] + e1.z * ve[14] + e1.w * ve[15];
    int s = src[e], d = dst[e];
    float av = als[s] + ald[d] + a0;
    av = av > 0.f ? av : 0.2f * av;
    float ex0 = __expf(av);
    int pos = rp[d] + rank[e];
    uint4 rec;
    rec.x = (unsigned)s;
    rec.y = __float_as_uint(ex0);
    rec.z = __float_as_uint(a1);
    rec.w = 0u;
    pk[pos] = rec;
}

// ---------------- MFMA GEMM: one wave = 16 rows x COLS, bf16x3 split precision ----------------
// B (Wth+Wtl) staged in LDS with XOR swizzle (row-major 256B rows = 16-way bank conflict
// without it; byte ^= ((row&7)<<4) spreads rows over 8 16B slots -> 2-way max, free).
// A loads hoisted before the staging barrier so their HBM latency hides under staging.
template<int COLS, bool BN_IN>
__launch_bounds__(256, 2)
__global__ void k_gemm_mfma(const float* __restrict__ A,
                            const unsigned short* __restrict__ Wth,
                            const unsigned short* __restrict__ Wtl,
                            unsigned short* __restrict__ out,
                            const float* __restrict__ a_src, const float* __restrict__ a_dst,
                            float* __restrict__ als, float* __restrict__ ald,
                            const float* __restrict__ bsum, const float* __restrict__ bsq,
                            const float* __restrict__ gamma, const float* __restrict__ beta)
{
    constexpr int NT = COLS / 16;
    __shared__ unsigned short sBh[COLS * 128];   // 32KB (COLS=128) / 28KB (112)
    __shared__ unsigned short sBl[COLS * 128];
    __shared__ float scN[128], shN[128];

    int wv = threadIdx.x >> 6;
    int lane = threadIdx.x & 63;
    int r0 = blockIdx.x * 64 + wv * 16;
    int m = lane & 15;
    int quad = lane >> 4;
    int arow = r0 + m;
    int rc = (arow < NN) ? arow : NN - 1;    // clamp: pad rows computed but never stored
    const float* pa = A + (size_t)rc * 128 + quad * 8;

    // hoist A loads (issue before the barrier; complete during B staging)
    float4 av[8];
    #pragma unroll
    for (int ks = 0; ks < 4; ++ks) {
        av[2 * ks]     = *reinterpret_cast<const float4*>(pa + ks * 32);
        av[2 * ks + 1] = *reinterpret_cast<const float4*>(pa + ks * 32 + 4);
    }

    // stage B into LDS, swizzled: dest_byte = src_byte ^ ((row&7)<<4), row = byte>>8
    constexpr int CH = COLS * 128 * 2 / 16;      // 16B chunks: 2048 / 1792
    for (int i = threadIdx.x; i < CH; i += 256) {
        unsigned o = (unsigned)i * 16u;
        unsigned d = o ^ (((o >> 8) & 7u) << 4);
        *reinterpret_cast<uint4*>(reinterpret_cast<char*>(sBh) + d) =
            *reinterpret_cast<const uint4*>(reinterpret_cast<const char*>(Wth) + o);
        *reinterpret_cast<uint4*>(reinterpret_cast<char*>(sBl) + d) =
            *reinterpret_cast<const uint4*>(reinterpret_cast<const char*>(Wtl) + o);
    }
    if (BN_IN) {
        if (threadIdx.x < 128) {
            int k = threadIdx.x;
            float invn = 1.0f / (float)NN;
            float mean = bsum[k] * invn;
            float var  = bsq[k] * invn - mean * mean;
            float sc = gamma[k] * rsqrtf(var + 1e-5f);
            scN[k] = sc;
            shN[k] = beta[k] - mean * sc;
        }
    }
    __syncthreads();

    f32x4 acc[NT];
    #pragma unroll
    for (int t = 0; t < NT; ++t) acc[t] = f32x4{0.f, 0.f, 0.f, 0.f};

    unsigned swz = ((unsigned)(m & 7)) << 4;     // loop-invariant lane swizzle (16 % 8 == 0)

    #pragma unroll
    for (int ks = 0; ks < 4; ++ks) {
        float4 v0 = av[2 * ks], v1 = av[2 * ks + 1];
        float vv[8] = {v0.x, v0.y, v0.z, v0.w, v1.x, v1.y, v1.z, v1.w};
        int kb = ks * 32 + quad * 8;
        bf16x8 ah, al;
        #pragma unroll
        for (int jj = 0; jj < 8; ++jj) {
            float f = vv[jj];
            if (BN_IN) f = fmaxf(f * scN[kb + jj] + shN[kb + jj], 0.f);
            unsigned short hi = f2bf(f);
            ah[jj] = (short)hi;
            al[jj] = (short)f2bf(f - bf2f(hi));
        }
        #pragma unroll
        for (int t = 0; t < NT; ++t) {
            int c = t * 16 + m;
            unsigned b = ((unsigned)c * 256u + (unsigned)ks * 64u + (unsigned)quad * 16u) ^ swz;
            bf16x8 bh = *reinterpret_cast<const bf16x8*>(reinterpret_cast<const char*>(sBh) + b);
            bf16x8 bl = *reinterpret_cast<const bf16x8*>(reinterpret_cast<const char*>(sBl) + b);
            acc[t] = __builtin_amdgcn_mfma_f32_16x16x32_bf16(ah, bh, acc[t], 0, 0, 0);
            acc[t] = __builtin_amdgcn_mfma_f32_16x16x32_bf16(al, bh, acc[t], 0, 0, 0);
            acc[t] = __builtin_amdgcn_mfma_f32_16x16x32_bf16(ah, bl, acc[t], 0, 0, 0);
        }
    }

    // epilogue: bf16 store + fused attention dots (C/D: col=lane&15, row=quad*4+reg)
    float p[4] = {0.f, 0.f, 0.f, 0.f}, q[4] = {0.f, 0.f, 0.f, 0.f};
    #pragma unroll
    for (int t = 0; t < NT; ++t) {
        int c = t * 16 + m;
        float asv = a_src[c], adv = a_dst[c];
        #pragma unroll
        for (int rI = 0; rI < 4; ++rI) {
            float v = acc[t][rI];
            int row = r0 + quad * 4 + rI;
            if (row < NN) out[(size_t)row * COLS + c] = f2bf(v);
            p[rI] += v * asv;
            q[rI] += v * adv;
        }
    }
    #pragma unroll
    for (int rI = 0; rI < 4; ++rI) {
        #pragma unroll
        for (int off = 1; off <= 8; off <<= 1) {
            p[rI] += __shfl_xor(p[rI], off);
            q[rI] += __shfl_xor(q[rI], off);
        }
    }
    if (m == 0) {
        #pragma unroll
        for (int rI = 0; rI < 4; ++rI) {
            int row = r0 + quad * 4 + rI;
            if (row < NN) { als[row] = p[rI]; ald[row] = q[rI]; }
        }
    }
}

// ---------------- layer-1 logit+exp: quarter-per-node, coalesced 16B reads -> 8B writes -----
__global__ void k_logit1(const int* __restrict__ rp, const uint4* __restrict__ pk,
                         const float* __restrict__ als, const float* __restrict__ ald,
                         uint2* __restrict__ pe)
{
    int ql = threadIdx.x & 15;
    int w = blockIdx.x * 16 + (threadIdx.x >> 4);
    if (w >= NN) return;
    int beg = rp[w], end = rp[w + 1];
    float aldv = ald[w];
    for (int p = beg + ql; p < end; p += 16) {
        uint4 r = pk[p];
        float a = als[r.x] + aldv + __uint_as_float(r.z);
        a = a > 0.f ? a : 0.2f * a;
        uint2 o;
        o.x = r.x;
        o.y = __float_as_uint(__expf(a));
        pe[p] = o;
    }
}

// ---------------- aggregate: QUARTER-PER-NODE, zero shuffles, fused BN partials -------------
// 16 lanes own one node's full row (16 x 8 cols). pe records are broadcast to the quarter;
// den is replicated per-lane (no reduce). 4 gathers in flight per lane; the 4 quarters of a
// wave advance through independent nodes, so segment-end drains don't stall the wave.
// RSTRIDE: pe record stride in uint2 units (2 for layer-0's 16B records, 1 for layer-1's 8B).
template<int COLS, int RSTRIDE>
__global__ void k_aggregate(const int* __restrict__ rp, const uint2* __restrict__ pe,
                            const unsigned short* __restrict__ xs, float* __restrict__ out,
                            float* __restrict__ psum, float* __restrict__ psq)
{
    __shared__ float sS[16 * 128], sQ[16 * 128];
    int ql = threadIdx.x & 15;
    int wq = threadIdx.x >> 4;               // 0..15 quarter slot within block
    int col = ql * 8;
    bool act = (col < COLS);
    int qid = blockIdx.x * 16 + wq;          // global quarter = node slot
    float bs[8] = {0.f,0.f,0.f,0.f,0.f,0.f,0.f,0.f};
    float bq[8] = {0.f,0.f,0.f,0.f,0.f,0.f,0.f,0.f};

    for (int w = qid; w < NN; w += AGG_NBLK * 16) {
        int beg = rp[w], end = rp[w + 1];
        float acc[8] = {0.f,0.f,0.f,0.f,0.f,0.f,0.f,0.f};
        float den = 0.f;
        int j = beg;
        // 4 edges/pass, 4 independent gathers in flight per lane
        for (; j + 4 <= end; j += 4) {
            uint2 r0 = pe[(size_t)(j    ) * RSTRIDE];
            uint2 r1 = pe[(size_t)(j + 1) * RSTRIDE];
            uint2 r2 = pe[(size_t)(j + 2) * RSTRIDE];
            uint2 r3 = pe[(size_t)(j + 3) * RSTRIDE];
            float e0 = __uint_as_float(r0.y);
            float e1 = __uint_as_float(r1.y);
            float e2 = __uint_as_float(r2.y);
            float e3 = __uint_as_float(r3.y);
            den += (e0 + e1) + (e2 + e3);
            if (act) {
                u16x8 u0 = *reinterpret_cast<const u16x8*>(xs + (size_t)r0.x * COLS + col);
                u16x8 u1 = *reinterpret_cast<const u16x8*>(xs + (size_t)r1.x * COLS + col);
                u16x8 u2 = *reinterpret_cast<const u16x8*>(xs + (size_t)r2.x * COLS + col);
                u16x8 u3 = *reinterpret_cast<const u16x8*>(xs + (size_t)r3.x * COLS + col);
                #pragma unroll
                for (int k = 0; k < 8; ++k)
                    acc[k] += (e0 * bf2f(u0[k]) + e1 * bf2f(u1[k]))
                            + (e2 * bf2f(u2[k]) + e3 * bf2f(u3[k]));
            }
        }
        // tail: one masked 4-slot pass (slot validity uniform across the quarter)
        if (j < end) {
            bool v1 = j + 1 < end;
            bool v2 = j + 2 < end;
            bool v3 = j + 3 < end;
            uint2 r0 = pe[(size_t)j * RSTRIDE];
            uint2 r1 = v1 ? pe[(size_t)(j + 1) * RSTRIDE] : uint2{0u, 0u};
            uint2 r2 = v2 ? pe[(size_t)(j + 2) * RSTRIDE] : uint2{0u, 0u};
            uint2 r3 = v3 ? pe[(size_t)(j + 3) * RSTRIDE] : uint2{0u, 0u};
            float e0 = __uint_as_float(r0.y);
            float e1 = __uint_as_float(r1.y);
            float e2 = __uint_as_float(r2.y);
            float e3 = __uint_as_float(r3.y);
            den += (e0 + e1) + (e2 + e3);
            if (act) {
                u16x8 u0 = *reinterpret_cast<const u16x8*>(xs + (size_t)r0.x * COLS + col);
                #pragma unroll
                for (int k = 0; k < 8; ++k) acc[k] += e0 * bf2f(u0[k]);
                if (v1) {
                    u16x8 u1 = *reinterpret_cast<const u16x8*>(xs + (size_t)r1.x * COLS + col);
                    #pragma unroll
                    for (int k = 0; k < 8; ++k) acc[k] += e1 * bf2f(u1[k]);
                }
                if (v2) {
                    u16x8 u2 = *reinterpret_cast<const u16x8*>(xs + (size_t)r2.x * COLS + col);
                    #pragma unroll
                    for (int k = 0; k < 8; ++k) acc[k] += e2 * bf2f(u2[k]);
                }
                if (v3) {
                    u16x8 u3 = *reinterpret_cast<const u16x8*>(xs + (size_t)r3.x * COLS + col);
                    #pragma unroll
                    for (int k = 0; k < 8; ++k) acc[k] += e3 * bf2f(u3[k]);
                }
            }
        }
        float inv = (end > beg) ? 1.f / den : 0.f;
        if (act) {
            float o[8];
            #pragma unroll
            for (int k = 0; k < 8; ++k) {
                o[k] = acc[k] * inv;
                bs[k] += o[k];
                bq[k] += o[k] * o[k];
            }
            f32x4 o0 = {o[0], o[1], o[2], o[3]};
            f32x4 o1 = {o[4], o[5], o[6], o[7]};
            __builtin_nontemporal_store(o0, reinterpret_cast<f32x4*>(out + (size_t)w * COLS + col));
            __builtin_nontemporal_store(o1, reinterpret_cast<f32x4*>(out + (size_t)w * COLS + col + 4));
        }
    }
    // fold BN partials across the block's 16 quarters (once per kernel)
    #pragma unroll
    for (int k = 0; k < 8; ++k) {
        sS[wq * 128 + col + k] = act ? bs[k] : 0.f;
        sQ[wq * 128 + col + k] = act ? bq[k] : 0.f;
    }
    __syncthreads();
    int t = threadIdx.x;
    if (t < 128) {
        float s = 0.f, s2 = 0.f;
        #pragma unroll
        for (int r = 0; r < 16; ++r) { s += sS[r * 128 + t]; s2 += sQ[r * 128 + t]; }
        psum[(size_t)blockIdx.x * 128 + t] = s;
        psq [(size_t)blockIdx.x * 128 + t] = s2;
    }
}

// ---------------- BN stats stage 2: reduce AGG_NBLK partials (lightly-contended atomics) ----
__global__ void k_bn_stats2(const float* __restrict__ psum, const float* __restrict__ psq,
                            float* __restrict__ sums, float* __restrict__ sqs)
{
    int t = threadIdx.x;
    int c = t & 127;
    constexpr int ROWS = AGG_NBLK / 128;    // 16
    const float* sp = (t < 128) ? psum : psq;
    float s = 0.f;
    #pragma unroll 4
    for (int i = 0; i < ROWS; ++i)
        s += sp[(size_t)(blockIdx.x * ROWS + i) * 128 + c];
    unsafeAtomicAdd(((t < 128) ? sums : sqs) + c, s);
}

// ---------------- batchnorm apply (final layer -> d_out) ----------------
template<int COLS>
__global__ void k_bn_apply(const float* __restrict__ in, float* __restrict__ out,
                           const float* __restrict__ sums, const float* __restrict__ sqs,
                           const float* __restrict__ gamma, const float* __restrict__ beta,
                           int n)
{
    int idx = blockIdx.x * blockDim.x + threadIdx.x;
    if (idx >= n * COLS) return;
    int c = idx % COLS;
    float invn = 1.0f / (float)n;
    float mean = sums[c] * invn;
    float var  = sqs[c] * invn - mean * mean;     // biased, matches jnp var
    float sc = gamma[c] * rsqrtf(var + 1e-5f);
    float sh = beta[c] - mean * sc;
    out[idx] = in[idx] * sc + sh;
}

extern "C" void kernel_launch(void* const* d_in, const int* in_sizes, int n_in,
                              void* d_out, int out_size, void* d_ws, size_t ws_size,
                              hipStream_t stream)
{
    const float* x    = (const float*)d_in[0];
    const int*   eidx = (const int*)d_in[1];
    const float* eatt = (const float*)d_in[2];
    const float* W0   = (const float*)d_in[3];
    const float* as0  = (const float*)d_in[4];
    const float* ad0  = (const float*)d_in[5];
    const float* We0  = (const float*)d_in[6];
    const float* ae0  = (const float*)d_in[7];
    // d_in[8] = b0 : cancels through BN
    const float* W1   = (const float*)d_in[9];
    const float* as1  = (const float*)d_in[10];
    const float* ad1  = (const float*)d_in[11];
    const float* We1  = (const float*)d_in[12];
    const float* ae1  = (const float*)d_in[13];
    // d_in[14] = b1 : cancels through BN
    const float* bng  = (const float*)d_in[15];
    const float* bnb  = (const float*)d_in[16];
    const float* bnfg = (const float*)d_in[17];
    const float* bnfb = (const float*)d_in[18];

    const int N = NN, E = NE;
    const int* src = eidx;
    const int* dst = eidx + E;

    float* ws = (float*)d_ws;
    size_t off = 0;
    unsigned short* xs0b = (unsigned short*)(ws + off); off += (size_t)N * 64;   // N*128 bf16
    float* h   = ws + off;      off += (size_t)N * 128;                          // fp32 25.6MB
    unsigned short* xs1b = (unsigned short*)(ws + off); off += (size_t)N * 56;   // N*112 bf16
    int*   rp   = (int*)(ws + off);     off += N + 2;
    int*   rank = (int*)(ws + off);     off += E;                                // per-edge rank
    int*   deg  = (int*)(ws + off);     off += N;
    float* als0 = ws + off;     off += N;
    float* ald0 = ws + off;     off += N;
    float* als1 = ws + off;     off += N;
    float* ald1 = ws + off;     off += N;
    float* stats = ws + off;    off += 512;
    float* ve = ws + off;       off += 16;
    int*   partial = (int*)(ws + off);  off += SCAN_NBLK;
    float* psum = ws + off;     off += (size_t)AGG_NBLK * 128;
    float* psq  = ws + off;     off += (size_t)AGG_NBLK * 128;
    unsigned short* Wth0 = (unsigned short*)(ws + off); off += 128 * 64;         // 128x128 bf16
    unsigned short* Wtl0 = (unsigned short*)(ws + off); off += 128 * 64;
    unsigned short* Wth1 = (unsigned short*)(ws + off); off += 112 * 64;         // 112x128 bf16
    unsigned short* Wtl1 = (unsigned short*)(ws + off); off += 112 * 64;
    float* out1 = h;            // alias: h (fp32) dead after layer-1 gemm consumes it

    // pk: 16B/edge records {src, ex0, a1_f32, 0} = 12.8MB, carved from d_out (22.4MB,
    // dead until k_bn_apply overwrites it). pe1: 8B/edge {src, ex1} right after (6.4MB).
    uint4* pk  = (uint4*)d_out;
    uint2* pe1 = (uint2*)((char*)d_out + (size_t)E * 16);

    float* sum0 = stats;
    float* sq0  = stats + 128;
    float* sum1 = stats + 256;
    float* sq1  = stats + 384;

    // ---- init (ws poisoned 0xAA before every call) ----
    k_init_cvt<<<(N + 255) / 256, 256, 0, stream>>>(deg, stats, We0, ae0, We1, ae1, ve,
                                                    W0, W1, Wth0, Wtl0, Wth1, Wtl1);

    // ---- CSR build: deg(+rank) -> scan ----
    k_deg<<<(E + 255) / 256, 256, 0, stream>>>(dst, deg, rank, E);
    k_scan1<<<SCAN_NBLK, SCAN_B, 0, stream>>>(deg, partial);
    k_scan3<<<SCAN_NBLK, SCAN_B, 0, stream>>>(deg, partial, rp);

    // ---- layer 0: 128 -> 128 (fill carries the layer-0 logit, so gemm0 runs first) ----
    k_gemm_mfma<128, false><<<NPAD / 64, 256, 0, stream>>>(x, Wth0, Wtl0, xs0b,
                                                           as0, ad0, als0, ald0,
                                                           nullptr, nullptr, nullptr, nullptr);
    k_csr_fill_l0<<<(E + 255) / 256, 256, 0, stream>>>(src, dst, eatt, ve, rp, rank,
                                                       als0, ald0, pk, E);
    k_aggregate<128, 2><<<AGG_NBLK, 256, 0, stream>>>(rp, (const uint2*)pk, xs0b, h, psum, psq);
    k_bn_stats2<<<128, 256, 0, stream>>>(psum, psq, sum0, sq0);

    // ---- layer 1: 128 -> 112 (BN0+ReLU fused into GEMM A-load) ----
    k_gemm_mfma<112, true><<<NPAD / 64, 256, 0, stream>>>(h, Wth1, Wtl1, xs1b,
                                                          as1, ad1, als1, ald1,
                                                          sum0, sq0, bng, bnb);
    k_logit1<<<(N + 15) / 16, 256, 0, stream>>>(rp, pk, als1, ald1, pe1);
    k_aggregate<112, 1><<<AGG_NBLK, 256, 0, stream>>>(rp, pe1, xs1b, out1, psum, psq);
    k_bn_stats2<<<128, 256, 0, stream>>>(psum, psq, sum1, sq1);
    k_bn_apply<112><<<(N * 112 + 255) / 256, 256, 0, stream>>>(out1, (float*)d_out, sum1, sq1, bnfg, bnfb, N);
}